// Round 1
// 290.312 us; speedup vs baseline: 1.0931x; 1.0931x over previous
//
#include <hip/hip_runtime.h>
#include <math.h>

#define BB 512
#define SS 200
#define DDIM 64
#define HD 32
#define LL 2
#define NROWS (BB * SS)   // 102400
#define EPS 1e-8f
#define CC 0.001f
#define GRAM_NB 256       // blocks PER INPUT; combined kernel launches 2*GRAM_NB
#define LSTRIDE 72

typedef __attribute__((ext_vector_type(8))) short bf16x8;
typedef __attribute__((ext_vector_type(4))) float f32x4;

// ---------------- static device buffers (activations) ----------------
__device__ float g_x[NROWS * DDIM];
__device__ unsigned short g_ctx[NROWS * DDIM];
__device__ unsigned short g_qb[NROWS * DDIM];   // also reused as bf16 x for gram-FF
__device__ unsigned short g_kb[NROWS * DDIM];
__device__ unsigned short g_vb[NROWS * DDIM];
__device__ float g_gpart[2 * GRAM_NB * 4096];   // gram per-block partials (EE slabs then FF slabs)

// ---------------- helpers ----------------
__device__ __forceinline__ float wave_sum(float v) {
#pragma unroll
    for (int o = 32; o > 0; o >>= 1) v += __shfl_xor(v, o, 64);
    return v;
}
__device__ __forceinline__ unsigned short f2b(float f) {
    unsigned u = __float_as_uint(f);
    return (unsigned short)((u + 0x7FFFu + ((u >> 16) & 1u)) >> 16);
}
__device__ __forceinline__ float b2f(unsigned short u) {
    return __uint_as_float(((unsigned)u) << 16);
}

// copy a bf16 global tile into LDS (stride 72)
__device__ __forceinline__ void stage_bf16_copy(const unsigned short* __restrict__ G, unsigned short* __restrict__ L,
                                                int t, long row0) {
#pragma unroll
    for (int rep = 0; rep < 4; ++rep) {
        int idx = t + rep * 256;
        int r = idx >> 4, c4 = (idx & 15) * 4;
        *(ushort4*)&L[r * LSTRIDE + c4] = *(const ushort4*)&G[(row0 + r) * DDIM + c4];
    }
}

__device__ __forceinline__ void stage_w_bf16(const float* __restrict__ Wg, unsigned short* __restrict__ L, int t) {
#pragma unroll
    for (int rep = 0; rep < 4; ++rep) {
        int idx = t + rep * 256;
        int r = idx >> 4, c4 = (idx & 15) * 4;
        float4 f = *(const float4*)&Wg[r * DDIM + c4];
        ushort4 o; o.x = f2b(f.x); o.y = f2b(f.y); o.z = f2b(f.z); o.w = f2b(f.w);
        *(ushort4*)&L[r * LSTRIDE + c4] = o;
    }
}

// LN(x rows) -> bf16 LDS tile. thread t: row t>>2, 16-col chunk (t&3)*16.
__device__ __forceinline__ void stage_ln_bf16(const float* __restrict__ x, unsigned short* __restrict__ L,
                                              const float* __restrict__ lnw, const float* __restrict__ lnb,
                                              int t, long row0) {
    int rr = t >> 2, qd = (t & 3) * 16;
    float4 v[4];
#pragma unroll
    for (int g = 0; g < 4; ++g) v[g] = *(const float4*)&x[(row0 + rr) * DDIM + qd + g * 4];
    float s1 = 0.f, s2 = 0.f;
#pragma unroll
    for (int g = 0; g < 4; ++g) {
        s1 += (v[g].x + v[g].y) + (v[g].z + v[g].w);
        s2 += (v[g].x * v[g].x + v[g].y * v[g].y) + (v[g].z * v[g].z + v[g].w * v[g].w);
    }
    s1 += __shfl_xor(s1, 1, 64); s1 += __shfl_xor(s1, 2, 64);
    s2 += __shfl_xor(s2, 1, 64); s2 += __shfl_xor(s2, 2, 64);
    float m = s1 * (1.f / 64.f);
    float var = s2 * (1.f / 64.f) - m * m;
    float rs = rsqrtf(var + EPS);
#pragma unroll
    for (int g = 0; g < 4; ++g) {
        float4 w4 = *(const float4*)&lnw[qd + g * 4];
        float4 b4 = *(const float4*)&lnb[qd + g * 4];
        ushort4 o;
        o.x = f2b((v[g].x - m) * rs * w4.x + b4.x);
        o.y = f2b((v[g].y - m) * rs * w4.y + b4.y);
        o.z = f2b((v[g].z - m) * rs * w4.z + b4.z);
        o.w = f2b((v[g].w - m) * rs * w4.w + b4.w);
        *(ushort4*)&L[rr * LSTRIDE + qd + g * 4] = o;
    }
}

// 64x64x64 GEMM slice for wave w: out rows w16..w16+15, all 64 cols.
__device__ __forceinline__ void mfma_gemm(const unsigned short* __restrict__ A,
                                          const unsigned short* __restrict__ B,
                                          int w16, int m16, int quad, f32x4 acc[4]) {
    bf16x8 a0 = *(const bf16x8*)&A[(w16 + m16) * LSTRIDE + quad * 8];
    bf16x8 a1 = *(const bf16x8*)&A[(w16 + m16) * LSTRIDE + 32 + quad * 8];
#pragma unroll
    for (int nt = 0; nt < 4; ++nt) {
        bf16x8 b0 = *(const bf16x8*)&B[(nt * 16 + m16) * LSTRIDE + quad * 8];
        bf16x8 b1 = *(const bf16x8*)&B[(nt * 16 + m16) * LSTRIDE + 32 + quad * 8];
        acc[nt] = __builtin_amdgcn_mfma_f32_16x16x32_bf16(a0, b0, acc[nt], 0, 0, 0);
        acc[nt] = __builtin_amdgcn_mfma_f32_16x16x32_bf16(a1, b1, acc[nt], 0, 0, 0);
    }
}

// ---------------- shared FFN core: Cb(ctx bf16) x W0 + residual-LN chain -> xv regs ----------------
__device__ __forceinline__ void ffn_core(unsigned short* Cb, unsigned short* Qb,
                                         const unsigned short* W0s,
                                         const unsigned short* W1s,
                                         const unsigned short* W2s,
                                         const float vecs[][64],
                                         int w16, int m16, int quad,
                                         float xv[4][4]) {
    f32x4 zero = {0.f, 0.f, 0.f, 0.f};
    f32x4 acc1[4] = {zero, zero, zero, zero};
    mfma_gemm(Cb, W0s, w16, m16, quad, acc1);
    float x1[4][4];
#pragma unroll
    for (int nt = 0; nt < 4; ++nt) {
        int n = nt * 16 + m16;
        float bb = vecs[0][n];
#pragma unroll
        for (int rg = 0; rg < 4; ++rg) {
            int m = w16 + quad * 4 + rg;
            x1[nt][rg] = acc1[nt][rg] + bb + b2f(Qb[m * LSTRIDE + n]);
        }
    }
    float ln1v[4][4], ln2v[4][4];
#pragma unroll
    for (int rg = 0; rg < 4; ++rg) {
        float s1 = (x1[0][rg] + x1[1][rg]) + (x1[2][rg] + x1[3][rg]);
        float s2 = x1[0][rg] * x1[0][rg] + x1[1][rg] * x1[1][rg]
                 + x1[2][rg] * x1[2][rg] + x1[3][rg] * x1[3][rg];
#pragma unroll
        for (int o = 1; o <= 8; o <<= 1) { s1 += __shfl_xor(s1, o, 64); s2 += __shfl_xor(s2, o, 64); }
        float mean = s1 * (1.f / 64.f);
        float var = s2 * (1.f / 64.f) - mean * mean;
        float rs = rsqrtf(var + EPS);
#pragma unroll
        for (int nt = 0; nt < 4; ++nt) {
            int n = nt * 16 + m16;
            float core = (x1[nt][rg] - mean) * rs;
            ln1v[nt][rg] = core * vecs[3][n] + vecs[4][n];
            ln2v[nt][rg] = core * vecs[5][n] + vecs[6][n];
        }
    }
    __builtin_amdgcn_wave_barrier();
#pragma unroll
    for (int nt = 0; nt < 4; ++nt)
#pragma unroll
        for (int rg = 0; rg < 4; ++rg)
            Cb[(w16 + quad * 4 + rg) * LSTRIDE + nt * 16 + m16] = f2b(ln1v[nt][rg]);
    __builtin_amdgcn_wave_barrier();
    f32x4 acc2[4] = {zero, zero, zero, zero};
    mfma_gemm(Cb, W1s, w16, m16, quad, acc2);
    __builtin_amdgcn_wave_barrier();
#pragma unroll
    for (int nt = 0; nt < 4; ++nt) {
        int n = nt * 16 + m16;
        float bb = vecs[1][n];
#pragma unroll
        for (int rg = 0; rg < 4; ++rg)
            Qb[(w16 + quad * 4 + rg) * LSTRIDE + n] = f2b(fmaxf(acc2[nt][rg] + bb, 0.f));
    }
    __builtin_amdgcn_wave_barrier();
    f32x4 acc3[4] = {zero, zero, zero, zero};
    mfma_gemm(Qb, W2s, w16, m16, quad, acc3);
#pragma unroll
    for (int nt = 0; nt < 4; ++nt) {
        int n = nt * 16 + m16;
        float bb = vecs[2][n];
#pragma unroll
        for (int rg = 0; rg < 4; ++rg)
            xv[nt][rg] = acc3[nt][rg] + bb + ln2v[nt][rg];
    }
}

// ---------------- fused embed + layer-0 QKV ----------------
__global__ __launch_bounds__(256) void embed_qkv0(const int* __restrict__ log_seqs,
                                                  const float* __restrict__ item_emb,
                                                  const float* __restrict__ pos_emb,
                                                  const float* __restrict__ Wqkv,
                                                  const float* __restrict__ Bqkv,
                                                  const float* __restrict__ lnw,
                                                  const float* __restrict__ lnb,
                                                  float* __restrict__ x,
                                                  unsigned short* __restrict__ qo,
                                                  unsigned short* __restrict__ ko,
                                                  unsigned short* __restrict__ vo) {
    __shared__ unsigned short Ab[64 * LSTRIDE], Lb[64 * LSTRIDE];
    __shared__ unsigned short Wq[64 * LSTRIDE], Wk[64 * LSTRIDE], Wv[64 * LSTRIDE];
    int t = threadIdx.x;
    long row0 = (long)blockIdx.x * 64;
    stage_w_bf16(Wqkv, Wq, t);
    stage_w_bf16(Wqkv + 4096, Wk, t);
    stage_w_bf16(Wqkv + 8192, Wv, t);
    // embed: thread t handles row rr, 16-col chunk qd (same mapping as stage_ln)
    int rr = t >> 2, qd = (t & 3) * 16;
    long row = row0 + rr;
    int li = log_seqs[row];
    int s = (int)(row % SS);
    int poss = li ? (s + 1) : 0;
    float4 v[4];
#pragma unroll
    for (int g = 0; g < 4; ++g) {
        float4 e = *(const float4*)&item_emb[(long)li * DDIM + qd + g * 4];
        float4 p = *(const float4*)&pos_emb[(long)poss * DDIM + qd + g * 4];
        v[g].x = e.x * 8.0f + p.x; v[g].y = e.y * 8.0f + p.y;
        v[g].z = e.z * 8.0f + p.z; v[g].w = e.w * 8.0f + p.w;
        *(float4*)&x[row * DDIM + qd + g * 4] = v[g];
        ushort4 o; o.x = f2b(v[g].x); o.y = f2b(v[g].y); o.z = f2b(v[g].z); o.w = f2b(v[g].w);
        *(ushort4*)&Ab[rr * LSTRIDE + qd + g * 4] = o;
    }
    // LN for Q input (same reduction order as stage_ln_bf16)
    float s1 = 0.f, s2 = 0.f;
#pragma unroll
    for (int g = 0; g < 4; ++g) {
        s1 += (v[g].x + v[g].y) + (v[g].z + v[g].w);
        s2 += (v[g].x * v[g].x + v[g].y * v[g].y) + (v[g].z * v[g].z + v[g].w * v[g].w);
    }
    s1 += __shfl_xor(s1, 1, 64); s1 += __shfl_xor(s1, 2, 64);
    s2 += __shfl_xor(s2, 1, 64); s2 += __shfl_xor(s2, 2, 64);
    float mean = s1 * (1.f / 64.f);
    float var = s2 * (1.f / 64.f) - mean * mean;
    float rs = rsqrtf(var + EPS);
#pragma unroll
    for (int g = 0; g < 4; ++g) {
        float4 w4 = *(const float4*)&lnw[qd + g * 4];
        float4 b4 = *(const float4*)&lnb[qd + g * 4];
        ushort4 o;
        o.x = f2b((v[g].x - mean) * rs * w4.x + b4.x);
        o.y = f2b((v[g].y - mean) * rs * w4.y + b4.y);
        o.z = f2b((v[g].z - mean) * rs * w4.z + b4.z);
        o.w = f2b((v[g].w - mean) * rs * w4.w + b4.w);
        *(ushort4*)&Lb[rr * LSTRIDE + qd + g * 4] = o;
    }
    __syncthreads();
    int w16 = (t >> 6) * 16, lane = t & 63, m16 = lane & 15, quad = lane >> 4;
    f32x4 zero = {0.f, 0.f, 0.f, 0.f};
    {
        f32x4 acc[4] = {zero, zero, zero, zero};
        mfma_gemm(Lb, Wq, w16, m16, quad, acc);
#pragma unroll
        for (int nt = 0; nt < 4; ++nt) {
            int n = nt * 16 + m16;
            float bb = Bqkv[n];
#pragma unroll
            for (int rg = 0; rg < 4; ++rg)
                qo[(row0 + w16 + quad * 4 + rg) * DDIM + n] = f2b(acc[nt][rg] + bb);
        }
    }
    {
        f32x4 acc[4] = {zero, zero, zero, zero};
        mfma_gemm(Ab, Wk, w16, m16, quad, acc);
#pragma unroll
        for (int nt = 0; nt < 4; ++nt) {
            int n = nt * 16 + m16;
            float bb = Bqkv[64 + n];
#pragma unroll
            for (int rg = 0; rg < 4; ++rg)
                ko[(row0 + w16 + quad * 4 + rg) * DDIM + n] = f2b(acc[nt][rg] + bb);
        }
    }
    {
        f32x4 acc[4] = {zero, zero, zero, zero};
        mfma_gemm(Ab, Wv, w16, m16, quad, acc);
#pragma unroll
        for (int nt = 0; nt < 4; ++nt) {
            int n = nt * 16 + m16;
            float bb = Bqkv[128 + n];
#pragma unroll
            for (int rg = 0; rg < 4; ++rg)
                vo[(row0 + w16 + quad * 4 + rg) * DDIM + n] = f2b(acc[nt][rg] + bb);
        }
    }
}

// ---------------- fused FFN(l) + QKV(l+1) ----------------
__global__ __launch_bounds__(256) void ffn_qkv(const unsigned short* __restrict__ ctx,
                                               const float* __restrict__ x,
                                               const float* __restrict__ Wo, const float* __restrict__ bo,
                                               const float* __restrict__ W1, const float* __restrict__ b1,
                                               const float* __restrict__ W2, const float* __restrict__ b2,
                                               const float* __restrict__ l0w, const float* __restrict__ l0b,
                                               const float* __restrict__ l1w, const float* __restrict__ l1b,
                                               const float* __restrict__ l2w, const float* __restrict__ l2b,
                                               const float* __restrict__ nlw, const float* __restrict__ nlb,
                                               const float* __restrict__ Wqkv, const float* __restrict__ Bqkv,
                                               float* __restrict__ xout,
                                               unsigned short* __restrict__ qo,
                                               unsigned short* __restrict__ ko,
                                               unsigned short* __restrict__ vo) {
    __shared__ unsigned short Cb[64 * LSTRIDE], Qb[64 * LSTRIDE];
    __shared__ unsigned short W0s[64 * LSTRIDE], W1s[64 * LSTRIDE], W2s[64 * LSTRIDE];
    __shared__ float vecs[9][64];   // bo,b1,b2,l1w,l1b,l2w,l2b,nlw,nlb
    int t = threadIdx.x;
    long row0 = (long)blockIdx.x * 64;
    stage_bf16_copy(ctx, Cb, t, row0);
    stage_ln_bf16(x, Qb, l0w, l0b, t, row0);   // qin = LN(x; ln0), bf16
    stage_w_bf16(Wo, W0s, t);
    stage_w_bf16(W1, W1s, t);
    stage_w_bf16(W2, W2s, t);
    if (t < 64) {
        vecs[0][t] = bo[t]; vecs[1][t] = b1[t]; vecs[2][t] = b2[t];
        vecs[3][t] = l1w[t]; vecs[4][t] = l1b[t]; vecs[5][t] = l2w[t]; vecs[6][t] = l2b[t];
        vecs[7][t] = nlw[t]; vecs[8][t] = nlb[t];
    }
    __syncthreads();
    int w16 = (t >> 6) * 16, lane = t & 63, m16 = lane & 15, quad = lane >> 4;
    float xv[4][4];
    ffn_core(Cb, Qb, W0s, W1s, W2s, vecs, w16, m16, quad, xv);
    // write new x (f32, needed by next ffn's stage_ln)
#pragma unroll
    for (int nt = 0; nt < 4; ++nt) {
        int n = nt * 16 + m16;
#pragma unroll
        for (int rg = 0; rg < 4; ++rg)
            xout[(row0 + w16 + quad * 4 + rg) * DDIM + n] = xv[nt][rg];
    }
    // LN for next-layer Q (16-lane reduce within quad group)
    float lnq[4][4];
#pragma unroll
    for (int rg = 0; rg < 4; ++rg) {
        float s1 = (xv[0][rg] + xv[1][rg]) + (xv[2][rg] + xv[3][rg]);
        float s2 = xv[0][rg] * xv[0][rg] + xv[1][rg] * xv[1][rg]
                 + xv[2][rg] * xv[2][rg] + xv[3][rg] * xv[3][rg];
#pragma unroll
        for (int o = 1; o <= 8; o <<= 1) { s1 += __shfl_xor(s1, o, 64); s2 += __shfl_xor(s2, o, 64); }
        float mean = s1 * (1.f / 64.f);
        float var = s2 * (1.f / 64.f) - mean * mean;
        float rs = rsqrtf(var + EPS);
#pragma unroll
        for (int nt = 0; nt < 4; ++nt) {
            int n = nt * 16 + m16;
            lnq[nt][rg] = (xv[nt][rg] - mean) * rs * vecs[7][n] + vecs[8][n];
        }
    }
    __syncthreads();   // all waves done with W/Cb/Qb of the FFN phase
    // restage: W <- next-layer QKV weights; Cb <- bf16 x; Qb <- bf16 LN(x)
    stage_w_bf16(Wqkv, W0s, t);
    stage_w_bf16(Wqkv + 4096, W1s, t);
    stage_w_bf16(Wqkv + 8192, W2s, t);
#pragma unroll
    for (int nt = 0; nt < 4; ++nt) {
        int n = nt * 16 + m16;
#pragma unroll
        for (int rg = 0; rg < 4; ++rg) {
            int m = w16 + quad * 4 + rg;
            Cb[m * LSTRIDE + n] = f2b(xv[nt][rg]);
            Qb[m * LSTRIDE + n] = f2b(lnq[nt][rg]);
        }
    }
    __syncthreads();
    f32x4 zero = {0.f, 0.f, 0.f, 0.f};
    {
        f32x4 acc[4] = {zero, zero, zero, zero};
        mfma_gemm(Qb, W0s, w16, m16, quad, acc);
#pragma unroll
        for (int nt = 0; nt < 4; ++nt) {
            int n = nt * 16 + m16;
            float bb = Bqkv[n];
#pragma unroll
            for (int rg = 0; rg < 4; ++rg)
                qo[(row0 + w16 + quad * 4 + rg) * DDIM + n] = f2b(acc[nt][rg] + bb);
        }
    }
    {
        f32x4 acc[4] = {zero, zero, zero, zero};
        mfma_gemm(Cb, W1s, w16, m16, quad, acc);
#pragma unroll
        for (int nt = 0; nt < 4; ++nt) {
            int n = nt * 16 + m16;
            float bb = Bqkv[64 + n];
#pragma unroll
            for (int rg = 0; rg < 4; ++rg)
                ko[(row0 + w16 + quad * 4 + rg) * DDIM + n] = f2b(acc[nt][rg] + bb);
        }
    }
    {
        f32x4 acc[4] = {zero, zero, zero, zero};
        mfma_gemm(Cb, W2s, w16, m16, quad, acc);
#pragma unroll
        for (int nt = 0; nt < 4; ++nt) {
            int n = nt * 16 + m16;
            float bb = Bqkv[128 + n];
#pragma unroll
            for (int rg = 0; rg < 4; ++rg)
                vo[(row0 + w16 + quad * 4 + rg) * DDIM + n] = f2b(acc[nt][rg] + bb);
        }
    }
}

// ---------------- fused FFN(last) + right() partial + bf16 x out ----------------
__global__ __launch_bounds__(256) void ffn_right(const unsigned short* __restrict__ ctx,
                                                 const float* __restrict__ x,
                                                 const float* __restrict__ Wo, const float* __restrict__ bo,
                                                 const float* __restrict__ W1, const float* __restrict__ b1,
                                                 const float* __restrict__ W2, const float* __restrict__ b2,
                                                 const float* __restrict__ l0w, const float* __restrict__ l0b,
                                                 const float* __restrict__ l1w, const float* __restrict__ l1b,
                                                 const float* __restrict__ l2w, const float* __restrict__ l2b,
                                                 const int* __restrict__ pos_seqs,
                                                 const float* __restrict__ item_emb,
                                                 const float* __restrict__ pred_w,
                                                 unsigned short* __restrict__ xb,
                                                 float* __restrict__ rpart) {
    __shared__ unsigned short Cb[64 * LSTRIDE], Qb[64 * LSTRIDE];
    __shared__ unsigned short W0s[64 * LSTRIDE], W1s[64 * LSTRIDE], W2s[64 * LSTRIDE];
    __shared__ float vecs[7][64];
    __shared__ float pw[64];
    __shared__ float red[4];
    int t = threadIdx.x;
    long row0 = (long)blockIdx.x * 64;
    stage_bf16_copy(ctx, Cb, t, row0);
    stage_ln_bf16(x, Qb, l0w, l0b, t, row0);
    stage_w_bf16(Wo, W0s, t);
    stage_w_bf16(W1, W1s, t);
    stage_w_bf16(W2, W2s, t);
    if (t < 64) {
        vecs[0][t] = bo[t]; vecs[1][t] = b1[t]; vecs[2][t] = b2[t];
        vecs[3][t] = l1w[t]; vecs[4][t] = l1b[t]; vecs[5][t] = l2w[t]; vecs[6][t] = l2b[t];
        pw[t] = pred_w[t];
    }
    __syncthreads();
    int w = t >> 6, w16 = w * 16, lane = t & 63, m16 = lane & 15, quad = lane >> 4;
    float xv[4][4];
    ffn_core(Cb, Qb, W0s, W1s, W2s, vecs, w16, m16, quad, xv);
    // bf16 x out (gram-FF input; identical to its former internal f2b conversion)
#pragma unroll
    for (int nt = 0; nt < 4; ++nt) {
        int n = nt * 16 + m16;
#pragma unroll
        for (int rg = 0; rg < 4; ++rg)
            xb[(row0 + w16 + quad * 4 + rg) * DDIM + n] = f2b(xv[nt][rg]);
    }
    // right(): ps = sum_d x[row,d]*item_emb[pos,d]*pred_w[d], from f32 regs
    float val[4];
#pragma unroll
    for (int rg = 0; rg < 4; ++rg) {
        long m = row0 + w16 + quad * 4 + rg;
        int pi = pos_seqs[m];
        float v = 0.f;
#pragma unroll
        for (int nt = 0; nt < 4; ++nt) {
            int n = nt * 16 + m16;
            v += xv[nt][rg] * item_emb[(long)pi * DDIM + n] * pw[n];
        }
        val[rg] = v;
    }
#pragma unroll
    for (int rg = 0; rg < 4; ++rg)
#pragma unroll
        for (int o = 1; o <= 8; o <<= 1) val[rg] += __shfl_xor(val[rg], o, 64);
    float local = 0.f;
    if (m16 == 0) {
#pragma unroll
        for (int rg = 0; rg < 4; ++rg) {
            float ps = val[rg];
            local += (1.0f - CC) * ps * ps - 2.0f * ps;
        }
    }
    local = wave_sum(local);
    if (lane == 0) red[w] = local;
    __syncthreads();
    if (t == 0) rpart[blockIdx.x] = red[0] + red[1] + red[2] + red[3];
}

// ---------------- MFMA flash attention, single-pass softmax, balanced waves ----------------
__global__ __launch_bounds__(256) void attn_kernel(const unsigned short* __restrict__ q,
                                                   const unsigned short* __restrict__ k,
                                                   const unsigned short* __restrict__ v,
                                                   unsigned short* __restrict__ ctx) {
    __shared__ unsigned short Kb[224 * 32];    // Kb[kk][d], zero for kk>=200
    __shared__ unsigned short Vt[32 * 232];    // Vt[d][kk], zero for kk>=200
    __shared__ unsigned short Ps[4][16 * 32];  // per-wave P buffer
    int b = blockIdx.x >> 1, h = blockIdx.x & 1;
    int t = threadIdx.x;
    const long base = (long)b * (SS * DDIM) + h * HD;
    for (int i = t; i < 224 * 4; i += 256) {   // 16B chunks (8 bf16)
        int kk = i >> 2, d8 = (i & 3) * 8;
        uint4 kv = make_uint4(0, 0, 0, 0), vv = make_uint4(0, 0, 0, 0);
        if (kk < SS) {
            kv = *(const uint4*)&k[base + kk * DDIM + d8];
            vv = *(const uint4*)&v[base + kk * DDIM + d8];
        }
        *(uint4*)&Kb[kk * 32 + d8] = kv;
        const unsigned short* vp = (const unsigned short*)&vv;
#pragma unroll
        for (int j = 0; j < 8; ++j) Vt[(d8 + j) * 232 + kk] = vp[j];
    }
    __syncthreads();
    int w = t >> 6, lane = t & 63;
    int m16 = lane & 15, quad = lane >> 4;
    const float scale = 0.17677669529663687f;   // 1/sqrt(32)
    unsigned short* ps = Ps[w];
    // balanced qt->wave map: per-wave pass totals {13,12,11,13} (was {16,9,12,12})
    const unsigned long long qpack = 0x3459F16AF27BF08Cull;
    for (int i = 0; i < 4; ++i) {
        int qt = (int)((qpack >> (w * 16 + i * 4)) & 15ull);
        if (qt == 15) continue;
        int q0 = qt * 16;
        int qrow = q0 + m16; if (qrow > SS - 1) qrow = SS - 1;
        bf16x8 qa = *(const bf16x8*)&q[base + qrow * DDIM + quad * 8];
        f32x4 o0 = {0.f, 0.f, 0.f, 0.f}, o1 = {0.f, 0.f, 0.f, 0.f};
        f32x4 s0a[7], s1a[7];
        float vmax[4] = {-1e30f, -1e30f, -1e30f, -1e30f};
        int np = (qt + 2) >> 1;
        // pass 1: all QK scores into registers, local max only
#pragma unroll
        for (int pi = 0; pi < 7; ++pi) {
            if (pi < np) {
                int p0 = pi * 32;
                bf16x8 kb0 = *(bf16x8*)&Kb[(p0 + m16) * 32 + quad * 8];
                bf16x8 kb1 = *(bf16x8*)&Kb[(p0 + 16 + m16) * 32 + quad * 8];
                f32x4 z = {0.f, 0.f, 0.f, 0.f};
                f32x4 s0 = __builtin_amdgcn_mfma_f32_16x16x32_bf16(qa, kb0, z, 0, 0, 0);
                f32x4 s1 = __builtin_amdgcn_mfma_f32_16x16x32_bf16(qa, kb1, z, 0, 0, 0);
                int col0 = p0 + m16, col1 = col0 + 16;
#pragma unroll
                for (int rg = 0; rg < 4; ++rg) {
                    int rglob = q0 + quad * 4 + rg;
                    float v0 = (col0 <= rglob && col0 < SS) ? s0[rg] * scale : -1e30f;
                    float v1 = (col1 <= rglob && col1 < SS) ? s1[rg] * scale : -1e30f;
                    s0a[pi][rg] = v0; s1a[pi][rg] = v1;
                    vmax[rg] = fmaxf(vmax[rg], fmaxf(v0, v1));
                }
            }
        }
        // row max reduce (once)
#pragma unroll
        for (int rg = 0; rg < 4; ++rg)
#pragma unroll
            for (int o = 1; o <= 8; o <<= 1) vmax[rg] = fmaxf(vmax[rg], __shfl_xor(vmax[rg], o, 64));
        // pass 2: exp, local sum, P -> LDS, PV MFMAs
        float lsum[4] = {0.f, 0.f, 0.f, 0.f};
#pragma unroll
        for (int pi = 0; pi < 7; ++pi) {
            if (pi < np) {
                int p0 = pi * 32;
                float e0[4], e1[4];
#pragma unroll
                for (int rg = 0; rg < 4; ++rg) {
                    e0[rg] = __expf(s0a[pi][rg] - vmax[rg]);
                    e1[rg] = __expf(s1a[pi][rg] - vmax[rg]);
                    lsum[rg] += e0[rg] + e1[rg];
                }
                __builtin_amdgcn_wave_barrier();
#pragma unroll
                for (int rg = 0; rg < 4; ++rg) {
                    int row = quad * 4 + rg;
                    ps[row * 32 + m16] = f2b(e0[rg]);
                    ps[row * 32 + 16 + m16] = f2b(e1[rg]);
                }
                __builtin_amdgcn_wave_barrier();
                bf16x8 pa = *(bf16x8*)&ps[m16 * 32 + quad * 8];
                bf16x8 vb0 = *(bf16x8*)&Vt[m16 * 232 + p0 + quad * 8];
                bf16x8 vb1 = *(bf16x8*)&Vt[(m16 + 16) * 232 + p0 + quad * 8];
                o0 = __builtin_amdgcn_mfma_f32_16x16x32_bf16(pa, vb0, o0, 0, 0, 0);
                o1 = __builtin_amdgcn_mfma_f32_16x16x32_bf16(pa, vb1, o1, 0, 0, 0);
            }
        }
        // row sum reduce (once)
#pragma unroll
        for (int rg = 0; rg < 4; ++rg)
#pragma unroll
            for (int o = 1; o <= 8; o <<= 1) lsum[rg] += __shfl_xor(lsum[rg], o, 64);
#pragma unroll
        for (int rg = 0; rg < 4; ++rg) {
            int rglob = q0 + quad * 4 + rg;
            if (rglob < SS) {
                float inv = 1.f / lsum[rg];
                ctx[base + rglob * DDIM + m16] = f2b(o0[rg] * inv);
                ctx[base + rglob * DDIM + 16 + m16] = f2b(o1[rg] * inv);
            }
        }
    }
}

// ---------------- MFMA Gram (combined EE f32 + FF bf16) ----------------
__global__ __launch_bounds__(256) void gram_kernel(const float* __restrict__ A0, int n0,
                                                   const unsigned short* __restrict__ A1, int n1,
                                                   float* __restrict__ part) {
    __shared__ unsigned short At[64 * LSTRIDE];   // At[c][r]
    int t = threadIdx.x;
    int second = blockIdx.x >= GRAM_NB;
    int bid = second ? blockIdx.x - GRAM_NB : blockIdx.x;
    int nrows = second ? n1 : n0;
    int w16 = (t >> 6) * 16, lane = t & 63, m16 = lane & 15, quad = lane >> 4;
    int bi = t & 15, bj = t >> 4;   // bi: col-block of A, bj: row-block
    f32x4 zero = {0.f, 0.f, 0.f, 0.f};
    f32x4 acc[4] = {zero, zero, zero, zero};
    for (long base = (long)bid * 64; base < nrows; base += (long)GRAM_NB * 64) {
        __syncthreads();   // protect At reads from previous iteration
        if (!second) {
            float rv[4][4];
#pragma unroll
            for (int e = 0; e < 4; ++e) {
                long gr = base + bj * 4 + e;
                float4 f = make_float4(0.f, 0.f, 0.f, 0.f);
                if (gr < nrows) f = *(const float4*)&A0[gr * DDIM + bi * 4];
                rv[e][0] = f.x; rv[e][1] = f.y; rv[e][2] = f.z; rv[e][3] = f.w;
            }
#pragma unroll
            for (int e = 0; e < 4; ++e) {
                ushort4 o;
                o.x = f2b(rv[0][e]); o.y = f2b(rv[1][e]); o.z = f2b(rv[2][e]); o.w = f2b(rv[3][e]);
                *(ushort4*)&At[(bi * 4 + e) * LSTRIDE + bj * 4] = o;
            }
        } else {
            ushort4 u[4];
#pragma unroll
            for (int e = 0; e < 4; ++e) {
                long gr = base + bj * 4 + e;
                ushort4 uu; uu.x = uu.y = uu.z = uu.w = 0;
                if (gr < nrows) uu = *(const ushort4*)&A1[gr * DDIM + bi * 4];
                u[e] = uu;
            }
#pragma unroll
            for (int e = 0; e < 4; ++e) {
                ushort4 o;
                o.x = ((const unsigned short*)&u[0])[e];
                o.y = ((const unsigned short*)&u[1])[e];
                o.z = ((const unsigned short*)&u[2])[e];
                o.w = ((const unsigned short*)&u[3])[e];
                *(ushort4*)&At[(bi * 4 + e) * LSTRIDE + bj * 4] = o;
            }
        }
        __syncthreads();
#pragma unroll
        for (int ks = 0; ks < 2; ++ks) {
            bf16x8 a = *(const bf16x8*)&At[(w16 + m16) * LSTRIDE + ks * 32 + quad * 8];
#pragma unroll
            for (int nt = 0; nt < 4; ++nt) {
                bf16x8 bfr = *(const bf16x8*)&At[(nt * 16 + m16) * LSTRIDE + ks * 32 + quad * 8];
                acc[nt] = __builtin_amdgcn_mfma_f32_16x16x32_bf16(a, bfr, acc[nt], 0, 0, 0);
            }
        }
    }
    float* slab = part + (long)blockIdx.x * 4096;
#pragma unroll
    for (int nt = 0; nt < 4; ++nt) {
        int n = nt * 16 + m16;
#pragma unroll
        for (int rg = 0; rg < 4; ++rg) {
            int m = w16 + quad * 4 + rg;
            slab[m * 64 + n] = acc[nt][rg];
        }
    }
}

// ---------------- per-parameter sum-of-squares ----------------
struct NormEntry { const float* p; int n; };
struct NormArgs { NormEntry e[30]; };

// blocks 0..31: gram reduce (0..15 EE, 16..31 FF); blocks 32..61: norms
__global__ __launch_bounds__(256) void reduce_norms(const float* __restrict__ part,
                                                    float* __restrict__ EE, float* __restrict__ FF,
                                                    NormArgs args, float* __restrict__ norms) {
    __shared__ float red[256];
    int blk = blockIdx.x;
    if (blk < 32) {
        int which = blk >> 4;
        int p = (blk & 15) * 256 + threadIdx.x;
        const float* basep = part + (long)which * GRAM_NB * 4096;
        float s = 0.f;
        for (int b = 0; b < GRAM_NB; ++b) s += basep[(long)b * 4096 + p];
        (which ? FF : EE)[p] = s;
    } else {
        NormEntry en = args.e[blk - 32];
        float s = 0.f;
        for (int i = threadIdx.x; i < en.n; i += 256) { float v = en.p[i]; s += v * v; }
        red[threadIdx.x] = s;
        for (int o = 128; o > 0; o >>= 1) {
            __syncthreads();
            if (threadIdx.x < o) red[threadIdx.x] += red[threadIdx.x + o];
        }
        __syncthreads();
        if (threadIdx.x == 0) norms[blk - 32] = red[0];
    }
}

// ---------------- final scalar ----------------
__global__ __launch_bounds__(256) void final_kernel(const float* __restrict__ EE,
                                                    const float* __restrict__ FF,
                                                    const float* __restrict__ pred_w,
                                                    const float* __restrict__ rpart,
                                                    const float* __restrict__ norms,
                                                    float* __restrict__ out) {
    __shared__ float p_s[64];
    __shared__ float redL[256];
    __shared__ float redT[256];
    __shared__ float redR[256];
    int t = threadIdx.x;
    if (t < 64) p_s[t] = pred_w[t];
    __syncthreads();
    float lf = 0.f, tr = 0.f, rs = 0.f;
    for (int p = t; p < 4096; p += 256) {
        int i = p >> 6, j = p & 63;
        float ee = EE[p];
        lf += FF[p] * ee * p_s[i] * p_s[j];
        if (i == j) tr += ee;
    }
    for (int i = t; i < 1600; i += 256) rs += rpart[i];
    redL[t] = lf; redT[t] = tr; redR[t] = rs;
    for (int o = 128; o > 0; o >>= 1) {
        __syncthreads();
        if (t < o) { redL[t] += redL[t + o]; redT[t] += redT[t + o]; redR[t] += redR[t + o]; }
    }
    __syncthreads();
    if (t == 0) {
        float reg = sqrtf(redT[0]);   // ||item_emb||_F = sqrt(trace(EE))
        for (int s = 0; s < 30; ++s) reg += sqrtf(norms[s]);
        out[0] = CC * redL[0] + redR[0] + 0.1f * reg;
    }
}

// ---------------- host ----------------
struct DevPtrs { float *x, *gpart; unsigned short *ctx, *qb, *kb, *vb; };

static DevPtrs fetch_ptrs() {
    DevPtrs p;
    (void)hipGetSymbolAddress((void**)&p.x,    HIP_SYMBOL(g_x));
    (void)hipGetSymbolAddress((void**)&p.ctx,  HIP_SYMBOL(g_ctx));
    (void)hipGetSymbolAddress((void**)&p.gpart,HIP_SYMBOL(g_gpart));
    (void)hipGetSymbolAddress((void**)&p.qb,   HIP_SYMBOL(g_qb));
    (void)hipGetSymbolAddress((void**)&p.kb,   HIP_SYMBOL(g_kb));
    (void)hipGetSymbolAddress((void**)&p.vb,   HIP_SYMBOL(g_vb));
    return p;
}

extern "C" void kernel_launch(void* const* d_in, const int* in_sizes, int n_in,
                              void* d_out, int out_size, void* d_ws, size_t ws_size,
                              hipStream_t stream) {
    const int*   log_seqs = (const int*)d_in[1];
    const int*   pos_seqs = (const int*)d_in[2];
    const float* item_emb = (const float*)d_in[3];
    const float* pos_emb  = (const float*)d_in[4];
    const float* pred_w   = (const float*)d_in[5];
    const float* ln_w     = (const float*)d_in[6];
    const float* ln_b     = (const float*)d_in[7];
    const float* qkv_w    = (const float*)d_in[8];
    const float* qkv_b    = (const float*)d_in[9];
    const float* out_w    = (const float*)d_in[10];
    const float* out_b    = (const float*)d_in[11];
    const float* fc1_w    = (const float*)d_in[12];
    const float* fc1_b    = (const float*)d_in[13];
    const float* ffln_w   = (const float*)d_in[14];
    const float* ffln_b   = (const float*)d_in[15];
    const float* fc2_w    = (const float*)d_in[16];
    const float* fc2_b    = (const float*)d_in[17];
    const float* ffln2_w  = (const float*)d_in[18];
    const float* ffln2_b  = (const float*)d_in[19];

    static DevPtrs P = fetch_ptrs();   // first call is the uncaptured correctness call

    float* ws    = (float*)d_ws;
    float* rpart = ws;            // 1600
    float* nrm   = ws + 1664;     // 30
    float* EE    = ws + 2048;     // 4096
    float* FF    = ws + 6144;     // 4096

    const int GEMM_GRID = NROWS / 64;   // 1600

    // layer 0: embed + qkv fused
    embed_qkv0<<<GEMM_GRID, 256, 0, stream>>>(log_seqs, item_emb, pos_emb,
        qkv_w, qkv_b, ln_w, ln_b, P.x, P.qb, P.kb, P.vb);
    attn_kernel<<<BB * 2, 256, 0, stream>>>(P.qb, P.kb, P.vb, P.ctx);
    // ffn(l0) + qkv(l1) fused
    ffn_qkv<<<GEMM_GRID, 256, 0, stream>>>(
        P.ctx, P.x,
        out_w, out_b, fc1_w, fc1_b, fc2_w, fc2_b,
        ln_w, ln_b, ffln_w, ffln_b, ffln2_w, ffln2_b,
        ln_w + 64, ln_b + 64, qkv_w + 12288, qkv_b + 192,
        P.x, P.qb, P.kb, P.vb);
    attn_kernel<<<BB * 2, 256, 0, stream>>>(P.qb, P.kb, P.vb, P.ctx);
    // ffn(l1) + right() fused; x emitted bf16 into g_qb (attn is done with it)
    ffn_right<<<GEMM_GRID, 256, 0, stream>>>(
        P.ctx, P.x,
        out_w + 4096, out_b + 64, fc1_w + 4096, fc1_b + 64, fc2_w + 4096, fc2_b + 64,
        ln_w + 64, ln_b + 64, ffln_w + 64, ffln_b + 64, ffln2_w + 64, ffln2_b + 64,
        pos_seqs, item_emb, pred_w,
        P.qb, rpart);

    gram_kernel<<<2 * GRAM_NB, 256, 0, stream>>>(item_emb, 100001, P.qb, NROWS, P.gpart);

    NormArgs na;
    int s = 0;
    na.e[s++] = {pos_emb, (SS + 1) * DDIM};
    na.e[s++] = {pred_w, DDIM};
    for (int l = 0; l < LL; ++l) {
        na.e[s++] = {ln_w + l * 64, 64};
        na.e[s++] = {ln_b + l * 64, 64};
        na.e[s++] = {qkv_w + (long)l * 12288, 12288};
        na.e[s++] = {qkv_b + (long)l * 192, 192};
        na.e[s++] = {out_w + (long)l * 4096, 4096};
        na.e[s++] = {out_b + l * 64, 64};
        na.e[s++] = {fc1_w + (long)l * 4096, 4096};
        na.e[s++] = {fc1_b + l * 64, 64};
        na.e[s++] = {ffln_w + l * 64, 64};
        na.e[s++] = {ffln_b + l * 64, 64};
        na.e[s++] = {fc2_w + (long)l * 4096, 4096};
        na.e[s++] = {fc2_b + l * 64, 64};
        na.e[s++] = {ffln2_w + l * 64, 64};
        na.e[s++] = {ffln2_b + l * 64, 64};
    }
    reduce_norms<<<62, 256, 0, stream>>>(P.gpart, EE, FF, na, nrm);

    final_kernel<<<1, 256, 0, stream>>>(EE, FF, pred_w, rpart, nrm, (float*)d_out);
}

// Round 2
// 276.999 us; speedup vs baseline: 1.1456x; 1.0481x over previous
//
#include <hip/hip_runtime.h>
#include <math.h>

#define BB 512
#define SS 200
#define DDIM 64
#define HD 32
#define LL 2
#define NROWS (BB * SS)   // 102400
#define EPS 1e-8f
#define CC 0.001f
#define GRAM_NB 256       // blocks PER INPUT; combined kernel launches 2*GRAM_NB
#define LSTRIDE 72

typedef __attribute__((ext_vector_type(8))) short bf16x8;
typedef __attribute__((ext_vector_type(4))) float f32x4;

// ---------------- static device buffers (activations) ----------------
__device__ float g_x[NROWS * DDIM];
__device__ unsigned short g_ctx[NROWS * DDIM];
__device__ unsigned short g_qb[NROWS * DDIM];   // also reused as bf16 x for gram-FF
__device__ unsigned short g_kb[NROWS * DDIM];
__device__ unsigned short g_vb[NROWS * DDIM];
__device__ float g_gpart[2 * GRAM_NB * 4096];   // gram per-block partials (EE slabs then FF slabs)
// pre-converted bf16 weights: qkv(2x12288)@0, out(2x4096)@24576, fc1@32768, fc2@40960
__device__ unsigned short g_wb[49152];

// ---------------- helpers ----------------
__device__ __forceinline__ float wave_sum(float v) {
#pragma unroll
    for (int o = 32; o > 0; o >>= 1) v += __shfl_xor(v, o, 64);
    return v;
}
__device__ __forceinline__ unsigned short f2b(float f) {
    unsigned u = __float_as_uint(f);
    return (unsigned short)((u + 0x7FFFu + ((u >> 16) & 1u)) >> 16);
}
__device__ __forceinline__ float b2f(unsigned short u) {
    return __uint_as_float(((unsigned)u) << 16);
}

// ---------------- one-time weight f32 -> bf16 conversion ----------------
__global__ __launch_bounds__(256) void prep_weights(const float* __restrict__ qkv_w,
                                                    const float* __restrict__ out_w,
                                                    const float* __restrict__ fc1_w,
                                                    const float* __restrict__ fc2_w,
                                                    unsigned short* __restrict__ wb) {
    int i4 = (blockIdx.x * 256 + threadIdx.x) * 4;   // grid 48 blocks covers 49152
    const float* src; int off;
    if (i4 < 24576)      { src = qkv_w; off = 0; }
    else if (i4 < 32768) { src = out_w; off = 24576; }
    else if (i4 < 40960) { src = fc1_w; off = 32768; }
    else                 { src = fc2_w; off = 40960; }
    float4 f = *(const float4*)&src[i4 - off];
    ushort4 o; o.x = f2b(f.x); o.y = f2b(f.y); o.z = f2b(f.z); o.w = f2b(f.w);
    *(ushort4*)&wb[i4] = o;
}

// copy a bf16 global tile (row-major 64x64) into LDS (stride 72)
__device__ __forceinline__ void stage_bf16_copy(const unsigned short* __restrict__ G, unsigned short* __restrict__ L,
                                                int t, long row0) {
#pragma unroll
    for (int rep = 0; rep < 4; ++rep) {
        int idx = t + rep * 256;
        int r = idx >> 4, c4 = (idx & 15) * 4;
        *(ushort4*)&L[r * LSTRIDE + c4] = *(const ushort4*)&G[(row0 + r) * DDIM + c4];
    }
}

// LN(x rows) -> bf16 LDS tile. thread t: row t>>2, 16-col chunk (t&3)*16.
__device__ __forceinline__ void stage_ln_bf16(const float* __restrict__ x, unsigned short* __restrict__ L,
                                              const float* __restrict__ lnw, const float* __restrict__ lnb,
                                              int t, long row0) {
    int rr = t >> 2, qd = (t & 3) * 16;
    float4 v[4];
#pragma unroll
    for (int g = 0; g < 4; ++g) v[g] = *(const float4*)&x[(row0 + rr) * DDIM + qd + g * 4];
    float s1 = 0.f, s2 = 0.f;
#pragma unroll
    for (int g = 0; g < 4; ++g) {
        s1 += (v[g].x + v[g].y) + (v[g].z + v[g].w);
        s2 += (v[g].x * v[g].x + v[g].y * v[g].y) + (v[g].z * v[g].z + v[g].w * v[g].w);
    }
    s1 += __shfl_xor(s1, 1, 64); s1 += __shfl_xor(s1, 2, 64);
    s2 += __shfl_xor(s2, 1, 64); s2 += __shfl_xor(s2, 2, 64);
    float m = s1 * (1.f / 64.f);
    float var = s2 * (1.f / 64.f) - m * m;
    float rs = rsqrtf(var + EPS);
#pragma unroll
    for (int g = 0; g < 4; ++g) {
        float4 w4 = *(const float4*)&lnw[qd + g * 4];
        float4 b4 = *(const float4*)&lnb[qd + g * 4];
        ushort4 o;
        o.x = f2b((v[g].x - m) * rs * w4.x + b4.x);
        o.y = f2b((v[g].y - m) * rs * w4.y + b4.y);
        o.z = f2b((v[g].z - m) * rs * w4.z + b4.z);
        o.w = f2b((v[g].w - m) * rs * w4.w + b4.w);
        *(ushort4*)&L[rr * LSTRIDE + qd + g * 4] = o;
    }
}

// 64x64x64 GEMM slice for wave w: out rows w16..w16+15, all 64 cols.
__device__ __forceinline__ void mfma_gemm(const unsigned short* __restrict__ A,
                                          const unsigned short* __restrict__ B,
                                          int w16, int m16, int quad, f32x4 acc[4]) {
    bf16x8 a0 = *(const bf16x8*)&A[(w16 + m16) * LSTRIDE + quad * 8];
    bf16x8 a1 = *(const bf16x8*)&A[(w16 + m16) * LSTRIDE + 32 + quad * 8];
#pragma unroll
    for (int nt = 0; nt < 4; ++nt) {
        bf16x8 b0 = *(const bf16x8*)&B[(nt * 16 + m16) * LSTRIDE + quad * 8];
        bf16x8 b1 = *(const bf16x8*)&B[(nt * 16 + m16) * LSTRIDE + 32 + quad * 8];
        acc[nt] = __builtin_amdgcn_mfma_f32_16x16x32_bf16(a0, b0, acc[nt], 0, 0, 0);
        acc[nt] = __builtin_amdgcn_mfma_f32_16x16x32_bf16(a1, b1, acc[nt], 0, 0, 0);
    }
}

// ---------------- shared FFN core: Cb(ctx bf16) x W0 + residual-LN chain -> xv regs ----------------
__device__ __forceinline__ void ffn_core(unsigned short* Cb, unsigned short* Qb,
                                         const unsigned short* W0s,
                                         const unsigned short* W1s,
                                         const unsigned short* W2s,
                                         const float vecs[][64],
                                         int w16, int m16, int quad,
                                         float xv[4][4]) {
    f32x4 zero = {0.f, 0.f, 0.f, 0.f};
    f32x4 acc1[4] = {zero, zero, zero, zero};
    mfma_gemm(Cb, W0s, w16, m16, quad, acc1);
    float x1[4][4];
#pragma unroll
    for (int nt = 0; nt < 4; ++nt) {
        int n = nt * 16 + m16;
        float bb = vecs[0][n];
#pragma unroll
        for (int rg = 0; rg < 4; ++rg) {
            int m = w16 + quad * 4 + rg;
            x1[nt][rg] = acc1[nt][rg] + bb + b2f(Qb[m * LSTRIDE + n]);
        }
    }
    float ln1v[4][4], ln2v[4][4];
#pragma unroll
    for (int rg = 0; rg < 4; ++rg) {
        float s1 = (x1[0][rg] + x1[1][rg]) + (x1[2][rg] + x1[3][rg]);
        float s2 = x1[0][rg] * x1[0][rg] + x1[1][rg] * x1[1][rg]
                 + x1[2][rg] * x1[2][rg] + x1[3][rg] * x1[3][rg];
#pragma unroll
        for (int o = 1; o <= 8; o <<= 1) { s1 += __shfl_xor(s1, o, 64); s2 += __shfl_xor(s2, o, 64); }
        float mean = s1 * (1.f / 64.f);
        float var = s2 * (1.f / 64.f) - mean * mean;
        float rs = rsqrtf(var + EPS);
#pragma unroll
        for (int nt = 0; nt < 4; ++nt) {
            int n = nt * 16 + m16;
            float core = (x1[nt][rg] - mean) * rs;
            ln1v[nt][rg] = core * vecs[3][n] + vecs[4][n];
            ln2v[nt][rg] = core * vecs[5][n] + vecs[6][n];
        }
    }
    __builtin_amdgcn_wave_barrier();
#pragma unroll
    for (int nt = 0; nt < 4; ++nt)
#pragma unroll
        for (int rg = 0; rg < 4; ++rg)
            Cb[(w16 + quad * 4 + rg) * LSTRIDE + nt * 16 + m16] = f2b(ln1v[nt][rg]);
    __builtin_amdgcn_wave_barrier();
    f32x4 acc2[4] = {zero, zero, zero, zero};
    mfma_gemm(Cb, W1s, w16, m16, quad, acc2);
    __builtin_amdgcn_wave_barrier();
#pragma unroll
    for (int nt = 0; nt < 4; ++nt) {
        int n = nt * 16 + m16;
        float bb = vecs[1][n];
#pragma unroll
        for (int rg = 0; rg < 4; ++rg)
            Qb[(w16 + quad * 4 + rg) * LSTRIDE + n] = f2b(fmaxf(acc2[nt][rg] + bb, 0.f));
    }
    __builtin_amdgcn_wave_barrier();
    f32x4 acc3[4] = {zero, zero, zero, zero};
    mfma_gemm(Qb, W2s, w16, m16, quad, acc3);
#pragma unroll
    for (int nt = 0; nt < 4; ++nt) {
        int n = nt * 16 + m16;
        float bb = vecs[2][n];
#pragma unroll
        for (int rg = 0; rg < 4; ++rg)
            xv[nt][rg] = acc3[nt][rg] + bb + ln2v[nt][rg];
    }
}

// ---------------- fused embed + layer-0 QKV ----------------
__global__ __launch_bounds__(256) void embed_qkv0(const int* __restrict__ log_seqs,
                                                  const float* __restrict__ item_emb,
                                                  const float* __restrict__ pos_emb,
                                                  const unsigned short* __restrict__ Wqkv_b,
                                                  const float* __restrict__ Bqkv,
                                                  const float* __restrict__ lnw,
                                                  const float* __restrict__ lnb,
                                                  float* __restrict__ x,
                                                  unsigned short* __restrict__ qo,
                                                  unsigned short* __restrict__ ko,
                                                  unsigned short* __restrict__ vo) {
    __shared__ unsigned short Ab[64 * LSTRIDE], Lb[64 * LSTRIDE];
    __shared__ unsigned short Wq[64 * LSTRIDE], Wk[64 * LSTRIDE], Wv[64 * LSTRIDE];
    int t = threadIdx.x;
    long row0 = (long)blockIdx.x * 64;
    stage_bf16_copy(Wqkv_b, Wq, t, 0);
    stage_bf16_copy(Wqkv_b + 4096, Wk, t, 0);
    stage_bf16_copy(Wqkv_b + 8192, Wv, t, 0);
    // embed: thread t handles row rr, 16-col chunk qd (same mapping as stage_ln)
    int rr = t >> 2, qd = (t & 3) * 16;
    long row = row0 + rr;
    int li = log_seqs[row];
    int s = (int)(row % SS);
    int poss = li ? (s + 1) : 0;
    float4 v[4];
#pragma unroll
    for (int g = 0; g < 4; ++g) {
        float4 e = *(const float4*)&item_emb[(long)li * DDIM + qd + g * 4];
        float4 p = *(const float4*)&pos_emb[(long)poss * DDIM + qd + g * 4];
        v[g].x = e.x * 8.0f + p.x; v[g].y = e.y * 8.0f + p.y;
        v[g].z = e.z * 8.0f + p.z; v[g].w = e.w * 8.0f + p.w;
        *(float4*)&x[row * DDIM + qd + g * 4] = v[g];
        ushort4 o; o.x = f2b(v[g].x); o.y = f2b(v[g].y); o.z = f2b(v[g].z); o.w = f2b(v[g].w);
        *(ushort4*)&Ab[rr * LSTRIDE + qd + g * 4] = o;
    }
    // LN for Q input (same reduction order as stage_ln_bf16)
    float s1 = 0.f, s2 = 0.f;
#pragma unroll
    for (int g = 0; g < 4; ++g) {
        s1 += (v[g].x + v[g].y) + (v[g].z + v[g].w);
        s2 += (v[g].x * v[g].x + v[g].y * v[g].y) + (v[g].z * v[g].z + v[g].w * v[g].w);
    }
    s1 += __shfl_xor(s1, 1, 64); s1 += __shfl_xor(s1, 2, 64);
    s2 += __shfl_xor(s2, 1, 64); s2 += __shfl_xor(s2, 2, 64);
    float mean = s1 * (1.f / 64.f);
    float var = s2 * (1.f / 64.f) - mean * mean;
    float rs = rsqrtf(var + EPS);
#pragma unroll
    for (int g = 0; g < 4; ++g) {
        float4 w4 = *(const float4*)&lnw[qd + g * 4];
        float4 b4 = *(const float4*)&lnb[qd + g * 4];
        ushort4 o;
        o.x = f2b((v[g].x - mean) * rs * w4.x + b4.x);
        o.y = f2b((v[g].y - mean) * rs * w4.y + b4.y);
        o.z = f2b((v[g].z - mean) * rs * w4.z + b4.z);
        o.w = f2b((v[g].w - mean) * rs * w4.w + b4.w);
        *(ushort4*)&Lb[rr * LSTRIDE + qd + g * 4] = o;
    }
    __syncthreads();
    int w16 = (t >> 6) * 16, lane = t & 63, m16 = lane & 15, quad = lane >> 4;
    f32x4 zero = {0.f, 0.f, 0.f, 0.f};
    {
        f32x4 acc[4] = {zero, zero, zero, zero};
        mfma_gemm(Lb, Wq, w16, m16, quad, acc);
#pragma unroll
        for (int nt = 0; nt < 4; ++nt) {
            int n = nt * 16 + m16;
            float bb = Bqkv[n];
#pragma unroll
            for (int rg = 0; rg < 4; ++rg)
                qo[(row0 + w16 + quad * 4 + rg) * DDIM + n] = f2b(acc[nt][rg] + bb);
        }
    }
    {
        f32x4 acc[4] = {zero, zero, zero, zero};
        mfma_gemm(Ab, Wk, w16, m16, quad, acc);
#pragma unroll
        for (int nt = 0; nt < 4; ++nt) {
            int n = nt * 16 + m16;
            float bb = Bqkv[64 + n];
#pragma unroll
            for (int rg = 0; rg < 4; ++rg)
                ko[(row0 + w16 + quad * 4 + rg) * DDIM + n] = f2b(acc[nt][rg] + bb);
        }
    }
    {
        f32x4 acc[4] = {zero, zero, zero, zero};
        mfma_gemm(Ab, Wv, w16, m16, quad, acc);
#pragma unroll
        for (int nt = 0; nt < 4; ++nt) {
            int n = nt * 16 + m16;
            float bb = Bqkv[128 + n];
#pragma unroll
            for (int rg = 0; rg < 4; ++rg)
                vo[(row0 + w16 + quad * 4 + rg) * DDIM + n] = f2b(acc[nt][rg] + bb);
        }
    }
}

// ---------------- fused FFN(l) + QKV(l+1) ----------------
__global__ __launch_bounds__(256) void ffn_qkv(const unsigned short* __restrict__ ctx,
                                               const float* __restrict__ x,
                                               const unsigned short* __restrict__ Wo_b, const float* __restrict__ bo,
                                               const unsigned short* __restrict__ W1_b, const float* __restrict__ b1,
                                               const unsigned short* __restrict__ W2_b, const float* __restrict__ b2,
                                               const float* __restrict__ l0w, const float* __restrict__ l0b,
                                               const float* __restrict__ l1w, const float* __restrict__ l1b,
                                               const float* __restrict__ l2w, const float* __restrict__ l2b,
                                               const float* __restrict__ nlw, const float* __restrict__ nlb,
                                               const unsigned short* __restrict__ Wqkv_b, const float* __restrict__ Bqkv,
                                               float* __restrict__ xout,
                                               unsigned short* __restrict__ qo,
                                               unsigned short* __restrict__ ko,
                                               unsigned short* __restrict__ vo) {
    __shared__ unsigned short Cb[64 * LSTRIDE], Qb[64 * LSTRIDE];
    __shared__ unsigned short W0s[64 * LSTRIDE], W1s[64 * LSTRIDE], W2s[64 * LSTRIDE];
    __shared__ float vecs[9][64];   // bo,b1,b2,l1w,l1b,l2w,l2b,nlw,nlb
    int t = threadIdx.x;
    long row0 = (long)blockIdx.x * 64;
    stage_bf16_copy(ctx, Cb, t, row0);
    stage_ln_bf16(x, Qb, l0w, l0b, t, row0);   // qin = LN(x; ln0), bf16
    stage_bf16_copy(Wo_b, W0s, t, 0);
    stage_bf16_copy(W1_b, W1s, t, 0);
    stage_bf16_copy(W2_b, W2s, t, 0);
    if (t < 64) {
        vecs[0][t] = bo[t]; vecs[1][t] = b1[t]; vecs[2][t] = b2[t];
        vecs[3][t] = l1w[t]; vecs[4][t] = l1b[t]; vecs[5][t] = l2w[t]; vecs[6][t] = l2b[t];
        vecs[7][t] = nlw[t]; vecs[8][t] = nlb[t];
    }
    __syncthreads();
    int w16 = (t >> 6) * 16, lane = t & 63, m16 = lane & 15, quad = lane >> 4;
    float xv[4][4];
    ffn_core(Cb, Qb, W0s, W1s, W2s, vecs, w16, m16, quad, xv);
    // write new x (f32, needed by next ffn's stage_ln)
#pragma unroll
    for (int nt = 0; nt < 4; ++nt) {
        int n = nt * 16 + m16;
#pragma unroll
        for (int rg = 0; rg < 4; ++rg)
            xout[(row0 + w16 + quad * 4 + rg) * DDIM + n] = xv[nt][rg];
    }
    // LN for next-layer Q (16-lane reduce within quad group)
    float lnq[4][4];
#pragma unroll
    for (int rg = 0; rg < 4; ++rg) {
        float s1 = (xv[0][rg] + xv[1][rg]) + (xv[2][rg] + xv[3][rg]);
        float s2 = xv[0][rg] * xv[0][rg] + xv[1][rg] * xv[1][rg]
                 + xv[2][rg] * xv[2][rg] + xv[3][rg] * xv[3][rg];
#pragma unroll
        for (int o = 1; o <= 8; o <<= 1) { s1 += __shfl_xor(s1, o, 64); s2 += __shfl_xor(s2, o, 64); }
        float mean = s1 * (1.f / 64.f);
        float var = s2 * (1.f / 64.f) - mean * mean;
        float rs = rsqrtf(var + EPS);
#pragma unroll
        for (int nt = 0; nt < 4; ++nt) {
            int n = nt * 16 + m16;
            lnq[nt][rg] = (xv[nt][rg] - mean) * rs * vecs[7][n] + vecs[8][n];
        }
    }
    __syncthreads();   // all waves done with W/Cb/Qb of the FFN phase
    // restage: W <- next-layer QKV weights; Cb <- bf16 x; Qb <- bf16 LN(x)
    stage_bf16_copy(Wqkv_b, W0s, t, 0);
    stage_bf16_copy(Wqkv_b + 4096, W1s, t, 0);
    stage_bf16_copy(Wqkv_b + 8192, W2s, t, 0);
#pragma unroll
    for (int nt = 0; nt < 4; ++nt) {
        int n = nt * 16 + m16;
#pragma unroll
        for (int rg = 0; rg < 4; ++rg) {
            int m = w16 + quad * 4 + rg;
            Cb[m * LSTRIDE + n] = f2b(xv[nt][rg]);
            Qb[m * LSTRIDE + n] = f2b(lnq[nt][rg]);
        }
    }
    __syncthreads();
    f32x4 zero = {0.f, 0.f, 0.f, 0.f};
    {
        f32x4 acc[4] = {zero, zero, zero, zero};
        mfma_gemm(Qb, W0s, w16, m16, quad, acc);
#pragma unroll
        for (int nt = 0; nt < 4; ++nt) {
            int n = nt * 16 + m16;
            float bb = Bqkv[n];
#pragma unroll
            for (int rg = 0; rg < 4; ++rg)
                qo[(row0 + w16 + quad * 4 + rg) * DDIM + n] = f2b(acc[nt][rg] + bb);
        }
    }
    {
        f32x4 acc[4] = {zero, zero, zero, zero};
        mfma_gemm(Cb, W1s, w16, m16, quad, acc);
#pragma unroll
        for (int nt = 0; nt < 4; ++nt) {
            int n = nt * 16 + m16;
            float bb = Bqkv[64 + n];
#pragma unroll
            for (int rg = 0; rg < 4; ++rg)
                ko[(row0 + w16 + quad * 4 + rg) * DDIM + n] = f2b(acc[nt][rg] + bb);
        }
    }
    {
        f32x4 acc[4] = {zero, zero, zero, zero};
        mfma_gemm(Cb, W2s, w16, m16, quad, acc);
#pragma unroll
        for (int nt = 0; nt < 4; ++nt) {
            int n = nt * 16 + m16;
            float bb = Bqkv[128 + n];
#pragma unroll
            for (int rg = 0; rg < 4; ++rg)
                vo[(row0 + w16 + quad * 4 + rg) * DDIM + n] = f2b(acc[nt][rg] + bb);
        }
    }
}

// ---------------- fused FFN(last) + right() partial + bf16 x out ----------------
__global__ __launch_bounds__(256) void ffn_right(const unsigned short* __restrict__ ctx,
                                                 const float* __restrict__ x,
                                                 const unsigned short* __restrict__ Wo_b, const float* __restrict__ bo,
                                                 const unsigned short* __restrict__ W1_b, const float* __restrict__ b1,
                                                 const unsigned short* __restrict__ W2_b, const float* __restrict__ b2,
                                                 const float* __restrict__ l0w, const float* __restrict__ l0b,
                                                 const float* __restrict__ l1w, const float* __restrict__ l1b,
                                                 const float* __restrict__ l2w, const float* __restrict__ l2b,
                                                 const int* __restrict__ pos_seqs,
                                                 const float* __restrict__ item_emb,
                                                 const float* __restrict__ pred_w,
                                                 unsigned short* __restrict__ xb,
                                                 float* __restrict__ rpart) {
    __shared__ unsigned short Cb[64 * LSTRIDE], Qb[64 * LSTRIDE];
    __shared__ unsigned short W0s[64 * LSTRIDE], W1s[64 * LSTRIDE], W2s[64 * LSTRIDE];
    __shared__ float vecs[7][64];
    __shared__ float pw[64];
    __shared__ float red[4];
    int t = threadIdx.x;
    long row0 = (long)blockIdx.x * 64;
    stage_bf16_copy(ctx, Cb, t, row0);
    stage_ln_bf16(x, Qb, l0w, l0b, t, row0);
    stage_bf16_copy(Wo_b, W0s, t, 0);
    stage_bf16_copy(W1_b, W1s, t, 0);
    stage_bf16_copy(W2_b, W2s, t, 0);
    if (t < 64) {
        vecs[0][t] = bo[t]; vecs[1][t] = b1[t]; vecs[2][t] = b2[t];
        vecs[3][t] = l1w[t]; vecs[4][t] = l1b[t]; vecs[5][t] = l2w[t]; vecs[6][t] = l2b[t];
        pw[t] = pred_w[t];
    }
    __syncthreads();
    int w = t >> 6, w16 = w * 16, lane = t & 63, m16 = lane & 15, quad = lane >> 4;
    float xv[4][4];
    ffn_core(Cb, Qb, W0s, W1s, W2s, vecs, w16, m16, quad, xv);
    // bf16 x out (gram-FF input; identical to its former internal f2b conversion)
#pragma unroll
    for (int nt = 0; nt < 4; ++nt) {
        int n = nt * 16 + m16;
#pragma unroll
        for (int rg = 0; rg < 4; ++rg)
            xb[(row0 + w16 + quad * 4 + rg) * DDIM + n] = f2b(xv[nt][rg]);
    }
    // right(): ps = sum_d x[row,d]*item_emb[pos,d]*pred_w[d], from f32 regs
    float val[4];
#pragma unroll
    for (int rg = 0; rg < 4; ++rg) {
        long m = row0 + w16 + quad * 4 + rg;
        int pi = pos_seqs[m];
        float v = 0.f;
#pragma unroll
        for (int nt = 0; nt < 4; ++nt) {
            int n = nt * 16 + m16;
            v += xv[nt][rg] * item_emb[(long)pi * DDIM + n] * pw[n];
        }
        val[rg] = v;
    }
#pragma unroll
    for (int rg = 0; rg < 4; ++rg)
#pragma unroll
        for (int o = 1; o <= 8; o <<= 1) val[rg] += __shfl_xor(val[rg], o, 64);
    float local = 0.f;
    if (m16 == 0) {
#pragma unroll
        for (int rg = 0; rg < 4; ++rg) {
            float ps = val[rg];
            local += (1.0f - CC) * ps * ps - 2.0f * ps;
        }
    }
    local = wave_sum(local);
    if (lane == 0) red[w] = local;
    __syncthreads();
    if (t == 0) rpart[blockIdx.x] = red[0] + red[1] + red[2] + red[3];
}

// ---------------- MFMA flash attention, single-pass (no-max softmax; scores provably tiny) ----------------
__global__ __launch_bounds__(256) void attn_kernel(const unsigned short* __restrict__ q,
                                                   const unsigned short* __restrict__ k,
                                                   const unsigned short* __restrict__ v,
                                                   unsigned short* __restrict__ ctx) {
    __shared__ unsigned short Kb[224 * 32];    // Kb[kk][d], zero for kk>=200
    __shared__ unsigned short Vt[32 * 232];    // Vt[d][kk], zero for kk>=200
    __shared__ unsigned short Ps[4][16 * 32];  // per-wave P buffer
    int b = blockIdx.x >> 1, h = blockIdx.x & 1;
    int t = threadIdx.x;
    const long base = (long)b * (SS * DDIM) + h * HD;
    for (int i = t; i < 224 * 4; i += 256) {   // 16B chunks (8 bf16)
        int kk = i >> 2, d8 = (i & 3) * 8;
        uint4 kv = make_uint4(0, 0, 0, 0), vv = make_uint4(0, 0, 0, 0);
        if (kk < SS) {
            kv = *(const uint4*)&k[base + kk * DDIM + d8];
            vv = *(const uint4*)&v[base + kk * DDIM + d8];
        }
        *(uint4*)&Kb[kk * 32 + d8] = kv;
        const unsigned short* vp = (const unsigned short*)&vv;
#pragma unroll
        for (int j = 0; j < 8; ++j) Vt[(d8 + j) * 232 + kk] = vp[j];
    }
    __syncthreads();
    int w = t >> 6, lane = t & 63;
    int m16 = lane & 15, quad = lane >> 4;
    const float scale = 0.17677669529663687f;   // 1/sqrt(32)
    unsigned short* ps = Ps[w];
    // balanced qt->wave map: per-wave pass totals {13,12,11,13}
    const unsigned long long qpack = 0x3459F16AF27BF08Cull;
    for (int i = 0; i < 4; ++i) {
        int qt = (int)((qpack >> (w * 16 + i * 4)) & 15ull);
        if (qt == 15) continue;
        int q0 = qt * 16;
        int qrow = q0 + m16; if (qrow > SS - 1) qrow = SS - 1;
        bf16x8 qa = *(const bf16x8*)&q[base + qrow * DDIM + quad * 8];
        f32x4 o0 = {0.f, 0.f, 0.f, 0.f}, o1 = {0.f, 0.f, 0.f, 0.f};
        float lsum[4] = {0.f, 0.f, 0.f, 0.f};
        int np = (qt + 2) >> 1;
        for (int pi = 0; pi < np; ++pi) {
            int p0 = pi * 32;
            bf16x8 kb0 = *(bf16x8*)&Kb[(p0 + m16) * 32 + quad * 8];
            bf16x8 kb1 = *(bf16x8*)&Kb[(p0 + 16 + m16) * 32 + quad * 8];
            f32x4 z = {0.f, 0.f, 0.f, 0.f};
            f32x4 s0 = __builtin_amdgcn_mfma_f32_16x16x32_bf16(qa, kb0, z, 0, 0, 0);
            f32x4 s1 = __builtin_amdgcn_mfma_f32_16x16x32_bf16(qa, kb1, z, 0, 0, 0);
            int col0 = p0 + m16, col1 = col0 + 16;
            float e0[4], e1[4];
#pragma unroll
            for (int rg = 0; rg < 4; ++rg) {
                int rglob = q0 + quad * 4 + rg;
                // exp without max-subtract: |scores| << 1 for this model scale, exactly 0 when masked
                e0[rg] = (col0 <= rglob && col0 < SS) ? __expf(s0[rg] * scale) : 0.f;
                e1[rg] = (col1 <= rglob && col1 < SS) ? __expf(s1[rg] * scale) : 0.f;
                lsum[rg] += e0[rg] + e1[rg];
            }
            __builtin_amdgcn_wave_barrier();
#pragma unroll
            for (int rg = 0; rg < 4; ++rg) {
                int row = quad * 4 + rg;
                ps[row * 32 + m16] = f2b(e0[rg]);
                ps[row * 32 + 16 + m16] = f2b(e1[rg]);
            }
            __builtin_amdgcn_wave_barrier();
            bf16x8 pa = *(bf16x8*)&ps[m16 * 32 + quad * 8];
            bf16x8 vb0 = *(bf16x8*)&Vt[m16 * 232 + p0 + quad * 8];
            bf16x8 vb1 = *(bf16x8*)&Vt[(m16 + 16) * 232 + p0 + quad * 8];
            o0 = __builtin_amdgcn_mfma_f32_16x16x32_bf16(pa, vb0, o0, 0, 0, 0);
            o1 = __builtin_amdgcn_mfma_f32_16x16x32_bf16(pa, vb1, o1, 0, 0, 0);
        }
        // row sum reduce (once)
#pragma unroll
        for (int rg = 0; rg < 4; ++rg)
#pragma unroll
            for (int o = 1; o <= 8; o <<= 1) lsum[rg] += __shfl_xor(lsum[rg], o, 64);
#pragma unroll
        for (int rg = 0; rg < 4; ++rg) {
            int rglob = q0 + quad * 4 + rg;
            if (rglob < SS) {
                float inv = 1.f / lsum[rg];
                ctx[base + rglob * DDIM + m16] = f2b(o0[rg] * inv);
                ctx[base + rglob * DDIM + 16 + m16] = f2b(o1[rg] * inv);
            }
        }
    }
}

// ---------------- MFMA Gram (combined EE f32 + FF bf16) ----------------
__global__ __launch_bounds__(256) void gram_kernel(const float* __restrict__ A0, int n0,
                                                   const unsigned short* __restrict__ A1, int n1,
                                                   float* __restrict__ part) {
    __shared__ unsigned short At[64 * LSTRIDE];   // At[c][r]
    int t = threadIdx.x;
    int second = blockIdx.x >= GRAM_NB;
    int bid = second ? blockIdx.x - GRAM_NB : blockIdx.x;
    int nrows = second ? n1 : n0;
    int w16 = (t >> 6) * 16, lane = t & 63, m16 = lane & 15, quad = lane >> 4;
    int bi = t & 15, bj = t >> 4;   // bi: col-block of A, bj: row-block
    f32x4 zero = {0.f, 0.f, 0.f, 0.f};
    f32x4 acc[4] = {zero, zero, zero, zero};
    for (long base = (long)bid * 64; base < nrows; base += (long)GRAM_NB * 64) {
        __syncthreads();   // protect At reads from previous iteration
        if (!second) {
            float rv[4][4];
#pragma unroll
            for (int e = 0; e < 4; ++e) {
                long gr = base + bj * 4 + e;
                float4 f = make_float4(0.f, 0.f, 0.f, 0.f);
                if (gr < nrows) f = *(const float4*)&A0[gr * DDIM + bi * 4];
                rv[e][0] = f.x; rv[e][1] = f.y; rv[e][2] = f.z; rv[e][3] = f.w;
            }
#pragma unroll
            for (int e = 0; e < 4; ++e) {
                ushort4 o;
                o.x = f2b(rv[0][e]); o.y = f2b(rv[1][e]); o.z = f2b(rv[2][e]); o.w = f2b(rv[3][e]);
                *(ushort4*)&At[(bi * 4 + e) * LSTRIDE + bj * 4] = o;
            }
        } else {
            ushort4 u[4];
#pragma unroll
            for (int e = 0; e < 4; ++e) {
                long gr = base + bj * 4 + e;
                ushort4 uu; uu.x = uu.y = uu.z = uu.w = 0;
                if (gr < nrows) uu = *(const ushort4*)&A1[gr * DDIM + bi * 4];
                u[e] = uu;
            }
#pragma unroll
            for (int e = 0; e < 4; ++e) {
                ushort4 o;
                o.x = ((const unsigned short*)&u[0])[e];
                o.y = ((const unsigned short*)&u[1])[e];
                o.z = ((const unsigned short*)&u[2])[e];
                o.w = ((const unsigned short*)&u[3])[e];
                *(ushort4*)&At[(bi * 4 + e) * LSTRIDE + bj * 4] = o;
            }
        }
        __syncthreads();
#pragma unroll
        for (int ks = 0; ks < 2; ++ks) {
            bf16x8 a = *(const bf16x8*)&At[(w16 + m16) * LSTRIDE + ks * 32 + quad * 8];
#pragma unroll
            for (int nt = 0; nt < 4; ++nt) {
                bf16x8 bfr = *(const bf16x8*)&At[(nt * 16 + m16) * LSTRIDE + ks * 32 + quad * 8];
                acc[nt] = __builtin_amdgcn_mfma_f32_16x16x32_bf16(a, bfr, acc[nt], 0, 0, 0);
            }
        }
    }
    float* slab = part + (long)blockIdx.x * 4096;
#pragma unroll
    for (int nt = 0; nt < 4; ++nt) {
        int n = nt * 16 + m16;
#pragma unroll
        for (int rg = 0; rg < 4; ++rg) {
            int m = w16 + quad * 4 + rg;
            slab[m * 64 + n] = acc[nt][rg];
        }
    }
}

// ---------------- per-parameter sum-of-squares ----------------
struct NormEntry { const float* p; int n; };
struct NormArgs { NormEntry e[30]; };

// blocks 0..31: gram reduce (0..15 EE, 16..31 FF); blocks 32..61: norms
__global__ __launch_bounds__(256) void reduce_norms(const float* __restrict__ part,
                                                    float* __restrict__ EE, float* __restrict__ FF,
                                                    NormArgs args, float* __restrict__ norms) {
    __shared__ float red[256];
    int blk = blockIdx.x;
    if (blk < 32) {
        int which = blk >> 4;
        int p = (blk & 15) * 256 + threadIdx.x;
        const float* basep = part + (long)which * GRAM_NB * 4096;
        float s = 0.f;
        for (int b = 0; b < GRAM_NB; ++b) s += basep[(long)b * 4096 + p];
        (which ? FF : EE)[p] = s;
    } else {
        NormEntry en = args.e[blk - 32];
        float s = 0.f;
        for (int i = threadIdx.x; i < en.n; i += 256) { float v = en.p[i]; s += v * v; }
        red[threadIdx.x] = s;
        for (int o = 128; o > 0; o >>= 1) {
            __syncthreads();
            if (threadIdx.x < o) red[threadIdx.x] += red[threadIdx.x + o];
        }
        __syncthreads();
        if (threadIdx.x == 0) norms[blk - 32] = red[0];
    }
}

// ---------------- final scalar ----------------
__global__ __launch_bounds__(256) void final_kernel(const float* __restrict__ EE,
                                                    const float* __restrict__ FF,
                                                    const float* __restrict__ pred_w,
                                                    const float* __restrict__ rpart,
                                                    const float* __restrict__ norms,
                                                    float* __restrict__ out) {
    __shared__ float p_s[64];
    __shared__ float redL[256];
    __shared__ float redT[256];
    __shared__ float redR[256];
    int t = threadIdx.x;
    if (t < 64) p_s[t] = pred_w[t];
    __syncthreads();
    float lf = 0.f, tr = 0.f, rs = 0.f;
    for (int p = t; p < 4096; p += 256) {
        int i = p >> 6, j = p & 63;
        float ee = EE[p];
        lf += FF[p] * ee * p_s[i] * p_s[j];
        if (i == j) tr += ee;
    }
    for (int i = t; i < 1600; i += 256) rs += rpart[i];
    redL[t] = lf; redT[t] = tr; redR[t] = rs;
    for (int o = 128; o > 0; o >>= 1) {
        __syncthreads();
        if (t < o) { redL[t] += redL[t + o]; redT[t] += redT[t + o]; redR[t] += redR[t + o]; }
    }
    __syncthreads();
    if (t == 0) {
        float reg = sqrtf(redT[0]);   // ||item_emb||_F = sqrt(trace(EE))
        for (int s = 0; s < 30; ++s) reg += sqrtf(norms[s]);
        out[0] = CC * redL[0] + redR[0] + 0.1f * reg;
    }
}

// ---------------- host ----------------
struct DevPtrs { float *x, *gpart; unsigned short *ctx, *qb, *kb, *vb, *wb; };

static DevPtrs fetch_ptrs() {
    DevPtrs p;
    (void)hipGetSymbolAddress((void**)&p.x,    HIP_SYMBOL(g_x));
    (void)hipGetSymbolAddress((void**)&p.ctx,  HIP_SYMBOL(g_ctx));
    (void)hipGetSymbolAddress((void**)&p.gpart,HIP_SYMBOL(g_gpart));
    (void)hipGetSymbolAddress((void**)&p.qb,   HIP_SYMBOL(g_qb));
    (void)hipGetSymbolAddress((void**)&p.kb,   HIP_SYMBOL(g_kb));
    (void)hipGetSymbolAddress((void**)&p.vb,   HIP_SYMBOL(g_vb));
    (void)hipGetSymbolAddress((void**)&p.wb,   HIP_SYMBOL(g_wb));
    return p;
}

extern "C" void kernel_launch(void* const* d_in, const int* in_sizes, int n_in,
                              void* d_out, int out_size, void* d_ws, size_t ws_size,
                              hipStream_t stream) {
    const int*   log_seqs = (const int*)d_in[1];
    const int*   pos_seqs = (const int*)d_in[2];
    const float* item_emb = (const float*)d_in[3];
    const float* pos_emb  = (const float*)d_in[4];
    const float* pred_w   = (const float*)d_in[5];
    const float* ln_w     = (const float*)d_in[6];
    const float* ln_b     = (const float*)d_in[7];
    const float* qkv_w    = (const float*)d_in[8];
    const float* qkv_b    = (const float*)d_in[9];
    const float* out_w    = (const float*)d_in[10];
    const float* out_b    = (const float*)d_in[11];
    const float* fc1_w    = (const float*)d_in[12];
    const float* fc1_b    = (const float*)d_in[13];
    const float* ffln_w   = (const float*)d_in[14];
    const float* ffln_b   = (const float*)d_in[15];
    const float* fc2_w    = (const float*)d_in[16];
    const float* fc2_b    = (const float*)d_in[17];
    const float* ffln2_w  = (const float*)d_in[18];
    const float* ffln2_b  = (const float*)d_in[19];

    static DevPtrs P = fetch_ptrs();   // first call is the uncaptured correctness call

    float* ws    = (float*)d_ws;
    float* rpart = ws;            // 1600
    float* nrm   = ws + 1664;     // 30
    float* EE    = ws + 2048;     // 4096
    float* FF    = ws + 6144;     // 4096

    const int GEMM_GRID = NROWS / 64;   // 1600

    // bf16 weight conversion (once per launch, ~2 us)
    prep_weights<<<48, 256, 0, stream>>>(qkv_w, out_w, fc1_w, fc2_w, P.wb);

    // layer 0: embed + qkv fused
    embed_qkv0<<<GEMM_GRID, 256, 0, stream>>>(log_seqs, item_emb, pos_emb,
        P.wb, qkv_b, ln_w, ln_b, P.x, P.qb, P.kb, P.vb);
    attn_kernel<<<BB * 2, 256, 0, stream>>>(P.qb, P.kb, P.vb, P.ctx);
    // ffn(l0) + qkv(l1) fused
    ffn_qkv<<<GEMM_GRID, 256, 0, stream>>>(
        P.ctx, P.x,
        P.wb + 24576, out_b, P.wb + 32768, fc1_b, P.wb + 40960, fc2_b,
        ln_w, ln_b, ffln_w, ffln_b, ffln2_w, ffln2_b,
        ln_w + 64, ln_b + 64, P.wb + 12288, qkv_b + 192,
        P.x, P.qb, P.kb, P.vb);
    attn_kernel<<<BB * 2, 256, 0, stream>>>(P.qb, P.kb, P.vb, P.ctx);
    // ffn(l1) + right() fused; x emitted bf16 into g_qb (attn is done with it)
    ffn_right<<<GEMM_GRID, 256, 0, stream>>>(
        P.ctx, P.x,
        P.wb + 24576 + 4096, out_b + 64, P.wb + 32768 + 4096, fc1_b + 64, P.wb + 40960 + 4096, fc2_b + 64,
        ln_w + 64, ln_b + 64, ffln_w + 64, ffln_b + 64, ffln2_w + 64, ffln2_b + 64,
        pos_seqs, item_emb, pred_w,
        P.qb, rpart);

    gram_kernel<<<2 * GRAM_NB, 256, 0, stream>>>(item_emb, 100001, P.qb, NROWS, P.gpart);

    NormArgs na;
    int s = 0;
    na.e[s++] = {pos_emb, (SS + 1) * DDIM};
    na.e[s++] = {pred_w, DDIM};
    for (int l = 0; l < LL; ++l) {
        na.e[s++] = {ln_w + l * 64, 64};
        na.e[s++] = {ln_b + l * 64, 64};
        na.e[s++] = {qkv_w + (long)l * 12288, 12288};
        na.e[s++] = {qkv_b + (long)l * 192, 192};
        na.e[s++] = {out_w + (long)l * 4096, 4096};
        na.e[s++] = {out_b + l * 64, 64};
        na.e[s++] = {fc1_w + (long)l * 4096, 4096};
        na.e[s++] = {fc1_b + l * 64, 64};
        na.e[s++] = {ffln_w + l * 64, 64};
        na.e[s++] = {ffln_b + l * 64, 64};
        na.e[s++] = {fc2_w + (long)l * 4096, 4096};
        na.e[s++] = {fc2_b + l * 64, 64};
        na.e[s++] = {ffln2_w + l * 64, 64};
        na.e[s++] = {ffln2_b + l * 64, 64};
    }
    reduce_norms<<<62, 256, 0, stream>>>(P.gpart, EE, FF, na, nrm);

    final_kernel<<<1, 256, 0, stream>>>(EE, FF, pred_w, rpart, nrm, (float*)d_out);
}

// Round 3
// 254.644 us; speedup vs baseline: 1.2462x; 1.0878x over previous
//
#include <hip/hip_runtime.h>
#include <math.h>

#define BB 512
#define SS 200
#define DDIM 64
#define HD 32
#define LL 2
#define NROWS (BB * SS)   // 102400
#define EPS 1e-8f
#define CC 0.001f
#define GRAM_NB 256       // blocks PER INPUT; combined kernel launches 2*GRAM_NB
#define LSTRIDE 72
#define XS 68             // Xf f32 LDS stride (68 -> 2-way-free column reads)

typedef __attribute__((ext_vector_type(8))) short bf16x8;
typedef __attribute__((ext_vector_type(4))) float f32x4;

// ---------------- static device buffers ----------------
__device__ unsigned short g_qb[NROWS * DDIM];   // final bf16 x (gram-FF input)
__device__ float g_gpart[2 * GRAM_NB * 4096];   // gram per-block partials (EE slabs then FF slabs)
// pre-converted bf16 weights: qkv(2x12288)@0, out(2x4096)@24576, fc1@32768, fc2@40960
__device__ unsigned short g_wb[49152];

// ---------------- helpers ----------------
__device__ __forceinline__ float wave_sum(float v) {
#pragma unroll
    for (int o = 32; o > 0; o >>= 1) v += __shfl_xor(v, o, 64);
    return v;
}
__device__ __forceinline__ unsigned short f2b(float f) {
    unsigned u = __float_as_uint(f);
    return (unsigned short)((u + 0x7FFFu + ((u >> 16) & 1u)) >> 16);
}

// ---------------- one-time weight f32 -> bf16 conversion ----------------
__global__ __launch_bounds__(256) void prep_weights(const float* __restrict__ qkv_w,
                                                    const float* __restrict__ out_w,
                                                    const float* __restrict__ fc1_w,
                                                    const float* __restrict__ fc2_w,
                                                    unsigned short* __restrict__ wb) {
    int i4 = (blockIdx.x * 256 + threadIdx.x) * 4;   // grid 48 blocks covers 49152
    const float* src; int off;
    if (i4 < 24576)      { src = qkv_w; off = 0; }
    else if (i4 < 32768) { src = out_w; off = 24576; }
    else if (i4 < 40960) { src = fc1_w; off = 32768; }
    else                 { src = fc2_w; off = 40960; }
    float4 f = *(const float4*)&src[i4 - off];
    ushort4 o; o.x = f2b(f.x); o.y = f2b(f.y); o.z = f2b(f.z); o.w = f2b(f.w);
    *(ushort4*)&wb[i4] = o;
}

// ---------------- fragment builders (from LDS f32 x + per-row LN stats) ----------------
__device__ __forceinline__ bf16x8 frag_raw(const float* Xf, int row, int c0) {
    const float* p = &Xf[row * XS + c0];
    float4 u = *(const float4*)p;
    float4 v = *(const float4*)(p + 4);
    bf16x8 r;
    r[0] = (short)f2b(u.x); r[1] = (short)f2b(u.y); r[2] = (short)f2b(u.z); r[3] = (short)f2b(u.w);
    r[4] = (short)f2b(v.x); r[5] = (short)f2b(v.y); r[6] = (short)f2b(v.z); r[7] = (short)f2b(v.w);
    return r;
}
__device__ __forceinline__ bf16x8 frag_ln(const float* Xf, const float* stats,
                                          const float* vw, const float* vb,
                                          int row, int c0) {
    float m = stats[row * 2], rs = stats[row * 2 + 1];
    const float* p = &Xf[row * XS + c0];
    float4 u = *(const float4*)p;
    float4 v = *(const float4*)(p + 4);
    bf16x8 r;
    r[0] = (short)f2b((u.x - m) * rs * vw[c0 + 0] + vb[c0 + 0]);
    r[1] = (short)f2b((u.y - m) * rs * vw[c0 + 1] + vb[c0 + 1]);
    r[2] = (short)f2b((u.z - m) * rs * vw[c0 + 2] + vb[c0 + 2]);
    r[3] = (short)f2b((u.w - m) * rs * vw[c0 + 3] + vb[c0 + 3]);
    r[4] = (short)f2b((v.x - m) * rs * vw[c0 + 4] + vb[c0 + 4]);
    r[5] = (short)f2b((v.y - m) * rs * vw[c0 + 5] + vb[c0 + 5]);
    r[6] = (short)f2b((v.z - m) * rs * vw[c0 + 6] + vb[c0 + 6]);
    r[7] = (short)f2b((v.w - m) * rs * vw[c0 + 7] + vb[c0 + 7]);
    return r;
}

__device__ __forceinline__ void gemm_acc(bf16x8 a0, bf16x8 a1, const unsigned short* W,
                                         int m16, int quad, f32x4 acc[4]) {
#pragma unroll
    for (int nt = 0; nt < 4; ++nt) {
        bf16x8 b0 = *(const bf16x8*)&W[(nt * 16 + m16) * LSTRIDE + quad * 8];
        bf16x8 b1 = *(const bf16x8*)&W[(nt * 16 + m16) * LSTRIDE + 32 + quad * 8];
        acc[nt] = __builtin_amdgcn_mfma_f32_16x16x32_bf16(a0, b0, acc[nt], 0, 0, 0);
        acc[nt] = __builtin_amdgcn_mfma_f32_16x16x32_bf16(a1, b1, acc[nt], 0, 0, 0);
    }
}

// stage one 64x64 bf16 weight tile global->LDS (stride 72), 512 threads
__device__ __forceinline__ void stage_w512(const unsigned short* G, unsigned short* L, int t) {
#pragma unroll
    for (int rep = 0; rep < 2; ++rep) {
        int idx = t + rep * 512;
        int r = idx >> 4, c4 = (idx & 15) * 4;
        *(ushort4*)&L[r * LSTRIDE + c4] = *(const ushort4*)&G[r * 64 + c4];
    }
}

// ---------------- mega kernel: one block per batch element ----------------
__global__ __launch_bounds__(512) void mega(const int* __restrict__ log_seqs,
                                            const int* __restrict__ pos_seqs,
                                            const float* __restrict__ item_emb,
                                            const float* __restrict__ pos_emb,
                                            const float* __restrict__ pred_w,
                                            const float* __restrict__ ln_w,  const float* __restrict__ ln_b,
                                            const float* __restrict__ qkv_b,
                                            const float* __restrict__ out_b,
                                            const float* __restrict__ fc1_b, const float* __restrict__ fc2_b,
                                            const float* __restrict__ ffln_w, const float* __restrict__ ffln_b,
                                            const float* __restrict__ ffln2_w, const float* __restrict__ ffln2_b,
                                            const unsigned short* __restrict__ wb,
                                            unsigned short* __restrict__ xb,
                                            float* __restrict__ rpart) {
    __shared__ float Xf[200 * XS];              // 54,400 B  f32 activations
    __shared__ unsigned short Qb[200 * 72];     // 28,800 B  q, then ctx in-place
    __shared__ unsigned short Kb[200 * 72];     // 28,800 B
    __shared__ unsigned short Vt[64 * 232];     // 29,696 B  V transposed [d][kk]
    __shared__ unsigned short Wb[64 * LSTRIDE]; // 9,216 B   weight tile; Ps area during attn
    __shared__ float stats[200 * 2];            // 1,600 B   per-row (mean, rs)
    __shared__ float vecs[13][64];              // 3,328 B
    __shared__ float redw[8];

    const int t = threadIdx.x, b = blockIdx.x;
    const int w = t >> 6, lane = t & 63, m16 = lane & 15, quad = lane >> 4;
    const f32x4 Z = {0.f, 0.f, 0.f, 0.f};

    if (t < 64) vecs[12][t] = pred_w[t];

    // ---- embed + layer-0 LN stats ----
    for (int half = 0; half < 2; ++half) {
        int rr = (t >> 2) + half * 128;
        if (rr < 200) {
            int li = log_seqs[b * SS + rr];
            int poss = li ? (rr + 1) : 0;
            int qd = (t & 3) * 16;
            float4 v[4];
#pragma unroll
            for (int g = 0; g < 4; ++g) {
                float4 e = *(const float4*)&item_emb[(long)li * DDIM + qd + g * 4];
                float4 p = *(const float4*)&pos_emb[(long)poss * DDIM + qd + g * 4];
                v[g].x = e.x * 8.0f + p.x; v[g].y = e.y * 8.0f + p.y;
                v[g].z = e.z * 8.0f + p.z; v[g].w = e.w * 8.0f + p.w;
                *(float4*)&Xf[rr * XS + qd + g * 4] = v[g];
            }
            float s1 = 0.f, s2 = 0.f;
#pragma unroll
            for (int g = 0; g < 4; ++g) {
                s1 += (v[g].x + v[g].y) + (v[g].z + v[g].w);
                s2 += (v[g].x * v[g].x + v[g].y * v[g].y) + (v[g].z * v[g].z + v[g].w * v[g].w);
            }
            s1 += __shfl_xor(s1, 1, 64); s1 += __shfl_xor(s1, 2, 64);
            s2 += __shfl_xor(s2, 1, 64); s2 += __shfl_xor(s2, 2, 64);
            float mean = s1 * (1.f / 64.f);
            float var = s2 * (1.f / 64.f) - mean * mean;
            float rs = rsqrtf(var + EPS);
            if ((t & 3) == 0) { stats[rr * 2] = mean; stats[rr * 2 + 1] = rs; }
        }
    }
    __syncthreads();

    for (int l = 0; l < LL; ++l) {
        if (t < 64) {
            vecs[0][t] = qkv_b[l * 192 + t];
            vecs[1][t] = qkv_b[l * 192 + 64 + t];
            vecs[2][t] = qkv_b[l * 192 + 128 + t];
            vecs[3][t] = ln_w[l * 64 + t];   vecs[4][t] = ln_b[l * 64 + t];
            vecs[5][t] = out_b[l * 64 + t];
            vecs[6][t] = fc1_b[l * 64 + t];  vecs[7][t] = fc2_b[l * 64 + t];
            vecs[8][t] = ffln_w[l * 64 + t]; vecs[9][t] = ffln_b[l * 64 + t];
            vecs[10][t] = ffln2_w[l * 64 + t]; vecs[11][t] = ffln2_b[l * 64 + t];
        }
        // ---- Q GEMM (A = LN(x)) ----
        stage_w512(wb + l * 12288, Wb, t);
        __syncthreads();
        for (int tb = w * 16; tb < 200; tb += 128) {
            int row = tb + m16; if (row > 199) row = 199;
            bf16x8 a0 = frag_ln(Xf, stats, vecs[3], vecs[4], row, quad * 8);
            bf16x8 a1 = frag_ln(Xf, stats, vecs[3], vecs[4], row, 32 + quad * 8);
            f32x4 acc[4] = {Z, Z, Z, Z};
            gemm_acc(a0, a1, Wb, m16, quad, acc);
#pragma unroll
            for (int nt = 0; nt < 4; ++nt) {
                int n = nt * 16 + m16; float bbv = vecs[0][n];
#pragma unroll
                for (int rg = 0; rg < 4; ++rg) {
                    int m = tb + quad * 4 + rg;
                    if (m < 200) Qb[m * 72 + n] = f2b(acc[nt][rg] + bbv);
                }
            }
        }
        __syncthreads();
        // ---- K GEMM (A = bf16(x)) ----
        stage_w512(wb + l * 12288 + 4096, Wb, t);
        __syncthreads();
        for (int tb = w * 16; tb < 200; tb += 128) {
            int row = tb + m16; if (row > 199) row = 199;
            bf16x8 a0 = frag_raw(Xf, row, quad * 8);
            bf16x8 a1 = frag_raw(Xf, row, 32 + quad * 8);
            f32x4 acc[4] = {Z, Z, Z, Z};
            gemm_acc(a0, a1, Wb, m16, quad, acc);
#pragma unroll
            for (int nt = 0; nt < 4; ++nt) {
                int n = nt * 16 + m16; float bbv = vecs[1][n];
#pragma unroll
                for (int rg = 0; rg < 4; ++rg) {
                    int m = tb + quad * 4 + rg;
                    if (m < 200) Kb[m * 72 + n] = f2b(acc[nt][rg] + bbv);
                }
            }
        }
        __syncthreads();
        // ---- V GEMM (A = bf16(x)), write transposed; zero-fill Vt cols 200..231 ----
        stage_w512(wb + l * 12288 + 8192, Wb, t);
        {
            int r2 = t >> 3, cc = 200 + ((t * 4) & 31);
            ushort4 z4; z4.x = z4.y = z4.z = z4.w = 0;
            *(ushort4*)&Vt[r2 * 232 + cc] = z4;
        }
        __syncthreads();
        for (int tb = w * 16; tb < 200; tb += 128) {
            int row = tb + m16; if (row > 199) row = 199;
            bf16x8 a0 = frag_raw(Xf, row, quad * 8);
            bf16x8 a1 = frag_raw(Xf, row, 32 + quad * 8);
            f32x4 acc[4] = {Z, Z, Z, Z};
            gemm_acc(a0, a1, Wb, m16, quad, acc);
#pragma unroll
            for (int nt = 0; nt < 4; ++nt) {
                int n = nt * 16 + m16; float bbv = vecs[2][n];
#pragma unroll
                for (int rg = 0; rg < 4; ++rg) {
                    int m = tb + quad * 4 + rg;
                    if (m < 200) Vt[n * 232 + m] = f2b(acc[nt][rg] + bbv);
                }
            }
        }
        __syncthreads();
        // ---- attention: 26 (head,qtile) units hand-balanced over 8 waves ----
        {
            unsigned short* ps = &Wb[w * 512];   // Wb repurposed as per-wave P buffers
            const unsigned long long s01 = 0x01030B1900020A18ull;
            const unsigned long long s23 = 0xFF050D17FF040C16ull;
            const unsigned long long s45 = 0xFF070F15FF060E14ull;
            const unsigned long long s67 = 0xFF091113FF081012ull;
            unsigned long long pair = (w & 4) ? ((w & 2) ? s67 : s45) : ((w & 2) ? s23 : s01);
            unsigned su = (unsigned)(pair >> ((w & 1) * 32));
            const float scale = 0.17677669529663687f;   // 1/sqrt(32)
            for (int slot = 0; slot < 4; ++slot) {
                int u = (su >> (slot * 8)) & 0xFF;
                if (u == 0xFF) break;
                int h = u & 1, qt = u >> 1;
                int q0 = qt * 16;
                int qrow = q0 + m16; if (qrow > 199) qrow = 199;
                bf16x8 qa = *(const bf16x8*)&Qb[qrow * 72 + h * 32 + quad * 8];
                f32x4 o0 = Z, o1 = Z;
                float lsum[4] = {0.f, 0.f, 0.f, 0.f};
                int np = (qt + 2) >> 1;
                for (int pi = 0; pi < np; ++pi) {
                    int p0 = pi * 32;
                    int kr0 = p0 + m16;      int kr0c = kr0 > 199 ? 199 : kr0;
                    int kr1 = p0 + 16 + m16; int kr1c = kr1 > 199 ? 199 : kr1;
                    bf16x8 kb0 = *(const bf16x8*)&Kb[kr0c * 72 + h * 32 + quad * 8];
                    bf16x8 kb1 = *(const bf16x8*)&Kb[kr1c * 72 + h * 32 + quad * 8];
                    f32x4 s0 = __builtin_amdgcn_mfma_f32_16x16x32_bf16(qa, kb0, Z, 0, 0, 0);
                    f32x4 s1 = __builtin_amdgcn_mfma_f32_16x16x32_bf16(qa, kb1, Z, 0, 0, 0);
                    float e0[4], e1[4];
#pragma unroll
                    for (int rg = 0; rg < 4; ++rg) {
                        int rglob = q0 + quad * 4 + rg;
                        e0[rg] = (kr0 <= rglob && kr0 < SS) ? __expf(s0[rg] * scale) : 0.f;
                        e1[rg] = (kr1 <= rglob && kr1 < SS) ? __expf(s1[rg] * scale) : 0.f;
                        lsum[rg] += e0[rg] + e1[rg];
                    }
                    __builtin_amdgcn_wave_barrier();
#pragma unroll
                    for (int rg = 0; rg < 4; ++rg) {
                        int row = quad * 4 + rg;
                        ps[row * 32 + m16] = f2b(e0[rg]);
                        ps[row * 32 + 16 + m16] = f2b(e1[rg]);
                    }
                    __builtin_amdgcn_wave_barrier();
                    bf16x8 pa = *(const bf16x8*)&ps[m16 * 32 + quad * 8];
                    bf16x8 vb0 = *(const bf16x8*)&Vt[(h * 32 + m16) * 232 + p0 + quad * 8];
                    bf16x8 vb1 = *(const bf16x8*)&Vt[(h * 32 + 16 + m16) * 232 + p0 + quad * 8];
                    o0 = __builtin_amdgcn_mfma_f32_16x16x32_bf16(pa, vb0, o0, 0, 0, 0);
                    o1 = __builtin_amdgcn_mfma_f32_16x16x32_bf16(pa, vb1, o1, 0, 0, 0);
                }
#pragma unroll
                for (int rg = 0; rg < 4; ++rg)
#pragma unroll
                    for (int o = 1; o <= 8; o <<= 1) lsum[rg] += __shfl_xor(lsum[rg], o, 64);
#pragma unroll
                for (int rg = 0; rg < 4; ++rg) {
                    int rglob = q0 + quad * 4 + rg;
                    if (rglob < SS) {
                        float inv = 1.f / lsum[rg];
                        Qb[rglob * 72 + h * 32 + m16] = f2b(o0[rg] * inv);        // ctx in-place
                        Qb[rglob * 72 + h * 32 + 16 + m16] = f2b(o1[rg] * inv);
                    }
                }
            }
        }
        __syncthreads();
        // ---- FFN pass1: x1 = ctx*Wo + bo + LN0(x); write x1 -> Xf, new stats ----
        stage_w512(wb + 24576 + l * 4096, Wb, t);
        __syncthreads();
        for (int tb = w * 16; tb < 200; tb += 128) {
            int row = tb + m16; if (row > 199) row = 199;
            bf16x8 a0 = *(const bf16x8*)&Qb[row * 72 + quad * 8];
            bf16x8 a1 = *(const bf16x8*)&Qb[row * 72 + 32 + quad * 8];
            f32x4 acc[4] = {Z, Z, Z, Z};
            gemm_acc(a0, a1, Wb, m16, quad, acc);
            float x1[4][4];
#pragma unroll
            for (int nt = 0; nt < 4; ++nt) {
                int n = nt * 16 + m16;
                float bbv = vecs[5][n], lw = vecs[3][n], lb = vecs[4][n];
#pragma unroll
                for (int rg = 0; rg < 4; ++rg) {
                    int m = tb + quad * 4 + rg; int mc = m > 199 ? 199 : m;
                    float qin = (Xf[mc * XS + n] - stats[mc * 2]) * stats[mc * 2 + 1] * lw + lb;
                    x1[nt][rg] = acc[nt][rg] + bbv + qin;
                }
            }
#pragma unroll
            for (int rg = 0; rg < 4; ++rg) {
                float s1 = (x1[0][rg] + x1[1][rg]) + (x1[2][rg] + x1[3][rg]);
                float s2 = x1[0][rg] * x1[0][rg] + x1[1][rg] * x1[1][rg]
                         + x1[2][rg] * x1[2][rg] + x1[3][rg] * x1[3][rg];
#pragma unroll
                for (int o = 1; o <= 8; o <<= 1) { s1 += __shfl_xor(s1, o, 64); s2 += __shfl_xor(s2, o, 64); }
                float mean = s1 * (1.f / 64.f);
                float var = s2 * (1.f / 64.f) - mean * mean;
                float rs = rsqrtf(var + EPS);
                int m = tb + quad * 4 + rg;
                if (m < 200) {
#pragma unroll
                    for (int nt = 0; nt < 4; ++nt) Xf[m * XS + nt * 16 + m16] = x1[nt][rg];
                    if (m16 == 0) { stats[m * 2] = mean; stats[m * 2 + 1] = rs; }
                }
            }
        }
        __syncthreads();
        // ---- FFN pass2: h = relu(LN1(x1)*W1 + b1) -> Qb ----
        stage_w512(wb + 32768 + l * 4096, Wb, t);
        __syncthreads();
        for (int tb = w * 16; tb < 200; tb += 128) {
            int row = tb + m16; if (row > 199) row = 199;
            bf16x8 a0 = frag_ln(Xf, stats, vecs[8], vecs[9], row, quad * 8);
            bf16x8 a1 = frag_ln(Xf, stats, vecs[8], vecs[9], row, 32 + quad * 8);
            f32x4 acc[4] = {Z, Z, Z, Z};
            gemm_acc(a0, a1, Wb, m16, quad, acc);
#pragma unroll
            for (int nt = 0; nt < 4; ++nt) {
                int n = nt * 16 + m16; float bbv = vecs[6][n];
#pragma unroll
                for (int rg = 0; rg < 4; ++rg) {
                    int m = tb + quad * 4 + rg;
                    if (m < 200) Qb[m * 72 + n] = f2b(fmaxf(acc[nt][rg] + bbv, 0.f));
                }
            }
        }
        __syncthreads();
        // ---- FFN pass3: x = h*W2 + b2 + LN2(x1) -> Xf, stats for next layer ----
        stage_w512(wb + 40960 + l * 4096, Wb, t);
        __syncthreads();
        for (int tb = w * 16; tb < 200; tb += 128) {
            int row = tb + m16; if (row > 199) row = 199;
            bf16x8 a0 = *(const bf16x8*)&Qb[row * 72 + quad * 8];
            bf16x8 a1 = *(const bf16x8*)&Qb[row * 72 + 32 + quad * 8];
            f32x4 acc[4] = {Z, Z, Z, Z};
            gemm_acc(a0, a1, Wb, m16, quad, acc);
            float xn[4][4];
#pragma unroll
            for (int nt = 0; nt < 4; ++nt) {
                int n = nt * 16 + m16;
                float bbv = vecs[7][n], lw = vecs[10][n], lb = vecs[11][n];
#pragma unroll
                for (int rg = 0; rg < 4; ++rg) {
                    int m = tb + quad * 4 + rg; int mc = m > 199 ? 199 : m;
                    float ln2 = (Xf[mc * XS + n] - stats[mc * 2]) * stats[mc * 2 + 1] * lw + lb;
                    xn[nt][rg] = acc[nt][rg] + bbv + ln2;
                }
            }
#pragma unroll
            for (int rg = 0; rg < 4; ++rg) {
                float s1 = (xn[0][rg] + xn[1][rg]) + (xn[2][rg] + xn[3][rg]);
                float s2 = xn[0][rg] * xn[0][rg] + xn[1][rg] * xn[1][rg]
                         + xn[2][rg] * xn[2][rg] + xn[3][rg] * xn[3][rg];
#pragma unroll
                for (int o = 1; o <= 8; o <<= 1) { s1 += __shfl_xor(s1, o, 64); s2 += __shfl_xor(s2, o, 64); }
                float mean = s1 * (1.f / 64.f);
                float var = s2 * (1.f / 64.f) - mean * mean;
                float rs = rsqrtf(var + EPS);
                int m = tb + quad * 4 + rg;
                if (m < 200) {
#pragma unroll
                    for (int nt = 0; nt < 4; ++nt) Xf[m * XS + nt * 16 + m16] = xn[nt][rg];
                    if (m16 == 0) { stats[m * 2] = mean; stats[m * 2 + 1] = rs; }
                }
            }
        }
        __syncthreads();
    }

    // ---- epilogue: bf16 x out (gram-FF input) ----
    for (int i = t; i < 3200; i += 512) {
        int r = i >> 4, c4 = (i & 15) * 4;
        float4 f = *(const float4*)&Xf[r * XS + c4];
        ushort4 o; o.x = f2b(f.x); o.y = f2b(f.y); o.z = f2b(f.z); o.w = f2b(f.w);
        *(ushort4*)&xb[((long)b * SS + r) * DDIM + c4] = o;
    }
    // ---- right(): ps = sum_d x*item_emb[pos]*pred_w ----
    float local = 0.f;
    for (int half = 0; half < 2; ++half) {
        int rr = (t >> 2) + half * 128;
        if (rr < 200) {
            int pi = pos_seqs[b * SS + rr];
            int qd = (t & 3) * 16;
            float v = 0.f;
#pragma unroll
            for (int g = 0; g < 4; ++g) {
                float4 xv = *(const float4*)&Xf[rr * XS + qd + g * 4];
                float4 iv = *(const float4*)&item_emb[(long)pi * DDIM + qd + g * 4];
                const float* pwp = &vecs[12][qd + g * 4];
                v += xv.x * iv.x * pwp[0] + xv.y * iv.y * pwp[1]
                   + xv.z * iv.z * pwp[2] + xv.w * iv.w * pwp[3];
            }
            v += __shfl_xor(v, 1, 64); v += __shfl_xor(v, 2, 64);
            if ((t & 3) == 0) local += (1.0f - CC) * v * v - 2.0f * v;
        }
    }
    local = wave_sum(local);
    if (lane == 0) redw[w] = local;
    __syncthreads();
    if (t == 0) {
        float s = 0.f;
#pragma unroll
        for (int i = 0; i < 8; ++i) s += redw[i];
        rpart[b] = s;
    }
}

// ---------------- MFMA Gram (combined EE f32 + FF bf16) ----------------
__global__ __launch_bounds__(256) void gram_kernel(const float* __restrict__ A0, int n0,
                                                   const unsigned short* __restrict__ A1, int n1,
                                                   float* __restrict__ part) {
    __shared__ unsigned short At[64 * LSTRIDE];   // At[c][r]
    int t = threadIdx.x;
    int second = blockIdx.x >= GRAM_NB;
    int bid = second ? blockIdx.x - GRAM_NB : blockIdx.x;
    int nrows = second ? n1 : n0;
    int w16 = (t >> 6) * 16, lane = t & 63, m16 = lane & 15, quad = lane >> 4;
    int bi = t & 15, bj = t >> 4;   // bi: col-block of A, bj: row-block
    f32x4 zero = {0.f, 0.f, 0.f, 0.f};
    f32x4 acc[4] = {zero, zero, zero, zero};
    for (long base = (long)bid * 64; base < nrows; base += (long)GRAM_NB * 64) {
        __syncthreads();   // protect At reads from previous iteration
        if (!second) {
            float rv[4][4];
#pragma unroll
            for (int e = 0; e < 4; ++e) {
                long gr = base + bj * 4 + e;
                float4 f = make_float4(0.f, 0.f, 0.f, 0.f);
                if (gr < nrows) f = *(const float4*)&A0[gr * DDIM + bi * 4];
                rv[e][0] = f.x; rv[e][1] = f.y; rv[e][2] = f.z; rv[e][3] = f.w;
            }
#pragma unroll
            for (int e = 0; e < 4; ++e) {
                ushort4 o;
                o.x = f2b(rv[0][e]); o.y = f2b(rv[1][e]); o.z = f2b(rv[2][e]); o.w = f2b(rv[3][e]);
                *(ushort4*)&At[(bi * 4 + e) * LSTRIDE + bj * 4] = o;
            }
        } else {
            ushort4 u[4];
#pragma unroll
            for (int e = 0; e < 4; ++e) {
                long gr = base + bj * 4 + e;
                ushort4 uu; uu.x = uu.y = uu.z = uu.w = 0;
                if (gr < nrows) uu = *(const ushort4*)&A1[gr * DDIM + bi * 4];
                u[e] = uu;
            }
#pragma unroll
            for (int e = 0; e < 4; ++e) {
                ushort4 o;
                o.x = ((const unsigned short*)&u[0])[e];
                o.y = ((const unsigned short*)&u[1])[e];
                o.z = ((const unsigned short*)&u[2])[e];
                o.w = ((const unsigned short*)&u[3])[e];
                *(ushort4*)&At[(bi * 4 + e) * LSTRIDE + bj * 4] = o;
            }
        }
        __syncthreads();
#pragma unroll
        for (int ks = 0; ks < 2; ++ks) {
            bf16x8 a = *(const bf16x8*)&At[(w16 + m16) * LSTRIDE + ks * 32 + quad * 8];
#pragma unroll
            for (int nt = 0; nt < 4; ++nt) {
                bf16x8 bfr = *(const bf16x8*)&At[(nt * 16 + m16) * LSTRIDE + ks * 32 + quad * 8];
                acc[nt] = __builtin_amdgcn_mfma_f32_16x16x32_bf16(a, bfr, acc[nt], 0, 0, 0);
            }
        }
    }
    float* slab = part + (long)blockIdx.x * 4096;
#pragma unroll
    for (int nt = 0; nt < 4; ++nt) {
        int n = nt * 16 + m16;
#pragma unroll
        for (int rg = 0; rg < 4; ++rg) {
            int m = w16 + quad * 4 + rg;
            slab[m * 64 + n] = acc[nt][rg];
        }
    }
}

// ---------------- per-parameter sum-of-squares ----------------
struct NormEntry { const float* p; int n; };
struct NormArgs { NormEntry e[30]; };

// blocks 0..31: gram reduce (0..15 EE, 16..31 FF); blocks 32..61: norms
__global__ __launch_bounds__(256) void reduce_norms(const float* __restrict__ part,
                                                    float* __restrict__ EE, float* __restrict__ FF,
                                                    NormArgs args, float* __restrict__ norms) {
    __shared__ float red[256];
    int blk = blockIdx.x;
    if (blk < 32) {
        int which = blk >> 4;
        int p = (blk & 15) * 256 + threadIdx.x;
        const float* basep = part + (long)which * GRAM_NB * 4096;
        float s = 0.f;
        for (int b = 0; b < GRAM_NB; ++b) s += basep[(long)b * 4096 + p];
        (which ? FF : EE)[p] = s;
    } else {
        NormEntry en = args.e[blk - 32];
        float s = 0.f;
        for (int i = threadIdx.x; i < en.n; i += 256) { float v = en.p[i]; s += v * v; }
        red[threadIdx.x] = s;
        for (int o = 128; o > 0; o >>= 1) {
            __syncthreads();
            if (threadIdx.x < o) red[threadIdx.x] += red[threadIdx.x + o];
        }
        __syncthreads();
        if (threadIdx.x == 0) norms[blk - 32] = red[0];
    }
}

// ---------------- final scalar ----------------
__global__ __launch_bounds__(256) void final_kernel(const float* __restrict__ EE,
                                                    const float* __restrict__ FF,
                                                    const float* __restrict__ pred_w,
                                                    const float* __restrict__ rpart,
                                                    const float* __restrict__ norms,
                                                    float* __restrict__ out) {
    __shared__ float p_s[64];
    __shared__ float redL[256];
    __shared__ float redT[256];
    __shared__ float redR[256];
    int t = threadIdx.x;
    if (t < 64) p_s[t] = pred_w[t];
    __syncthreads();
    float lf = 0.f, tr = 0.f, rs = 0.f;
    for (int p = t; p < 4096; p += 256) {
        int i = p >> 6, j = p & 63;
        float ee = EE[p];
        lf += FF[p] * ee * p_s[i] * p_s[j];
        if (i == j) tr += ee;
    }
    for (int i = t; i < 512; i += 256) rs += rpart[i];
    redL[t] = lf; redT[t] = tr; redR[t] = rs;
    for (int o = 128; o > 0; o >>= 1) {
        __syncthreads();
        if (t < o) { redL[t] += redL[t + o]; redT[t] += redT[t + o]; redR[t] += redR[t + o]; }
    }
    __syncthreads();
    if (t == 0) {
        float reg = sqrtf(redT[0]);   // ||item_emb||_F = sqrt(trace(EE))
        for (int s = 0; s < 30; ++s) reg += sqrtf(norms[s]);
        out[0] = CC * redL[0] + redR[0] + 0.1f * reg;
    }
}

// ---------------- host ----------------
struct DevPtrs { float* gpart; unsigned short *qb, *wb; };

static DevPtrs fetch_ptrs() {
    DevPtrs p;
    (void)hipGetSymbolAddress((void**)&p.gpart, HIP_SYMBOL(g_gpart));
    (void)hipGetSymbolAddress((void**)&p.qb,    HIP_SYMBOL(g_qb));
    (void)hipGetSymbolAddress((void**)&p.wb,    HIP_SYMBOL(g_wb));
    return p;
}

extern "C" void kernel_launch(void* const* d_in, const int* in_sizes, int n_in,
                              void* d_out, int out_size, void* d_ws, size_t ws_size,
                              hipStream_t stream) {
    const int*   log_seqs = (const int*)d_in[1];
    const int*   pos_seqs = (const int*)d_in[2];
    const float* item_emb = (const float*)d_in[3];
    const float* pos_emb  = (const float*)d_in[4];
    const float* pred_w   = (const float*)d_in[5];
    const float* ln_w     = (const float*)d_in[6];
    const float* ln_b     = (const float*)d_in[7];
    const float* qkv_w    = (const float*)d_in[8];
    const float* qkv_b    = (const float*)d_in[9];
    const float* out_w    = (const float*)d_in[10];
    const float* out_b    = (const float*)d_in[11];
    const float* fc1_w    = (const float*)d_in[12];
    const float* fc1_b    = (const float*)d_in[13];
    const float* ffln_w   = (const float*)d_in[14];
    const float* ffln_b   = (const float*)d_in[15];
    const float* fc2_w    = (const float*)d_in[16];
    const float* fc2_b    = (const float*)d_in[17];
    const float* ffln2_w  = (const float*)d_in[18];
    const float* ffln2_b  = (const float*)d_in[19];

    static DevPtrs P = fetch_ptrs();   // first call is the uncaptured correctness call

    float* ws    = (float*)d_ws;
    float* rpart = ws;            // 512
    float* nrm   = ws + 1664;     // 30
    float* EE    = ws + 2048;     // 4096
    float* FF    = ws + 6144;     // 4096

    // bf16 weight conversion (once per launch, ~2 us)
    prep_weights<<<48, 256, 0, stream>>>(qkv_w, out_w, fc1_w, fc2_w, P.wb);

    // the whole transformer + right(), one block per batch element
    mega<<<BB, 512, 0, stream>>>(log_seqs, pos_seqs, item_emb, pos_emb, pred_w,
                                 ln_w, ln_b, qkv_b, out_b, fc1_b, fc2_b,
                                 ffln_w, ffln_b, ffln2_w, ffln2_b,
                                 P.wb, P.qb, rpart);

    gram_kernel<<<2 * GRAM_NB, 256, 0, stream>>>(item_emb, 100001, P.qb, NROWS, P.gpart);

    NormArgs na;
    int s = 0;
    na.e[s++] = {pos_emb, (SS + 1) * DDIM};
    na.e[s++] = {pred_w, DDIM};
    for (int l = 0; l < LL; ++l) {
        na.e[s++] = {ln_w + l * 64, 64};
        na.e[s++] = {ln_b + l * 64, 64};
        na.e[s++] = {qkv_w + (long)l * 12288, 12288};
        na.e[s++] = {qkv_b + (long)l * 192, 192};
        na.e[s++] = {out_w + (long)l * 4096, 4096};
        na.e[s++] = {out_b + l * 64, 64};
        na.e[s++] = {fc1_w + (long)l * 4096, 4096};
        na.e[s++] = {fc1_b + l * 64, 64};
        na.e[s++] = {ffln_w + l * 64, 64};
        na.e[s++] = {ffln_b + l * 64, 64};
        na.e[s++] = {fc2_w + (long)l * 4096, 4096};
        na.e[s++] = {fc2_b + l * 64, 64};
        na.e[s++] = {ffln2_w + l * 64, 64};
        na.e[s++] = {ffln2_b + l * 64, 64};
    }
    reduce_norms<<<62, 256, 0, stream>>>(P.gpart, EE, FF, na, nrm);

    final_kernel<<<1, 256, 0, stream>>>(EE, FF, pred_w, rpart, nrm, (float*)d_out);
}